// Round 5
// baseline (9281.748 us; speedup 1.0000x reference)
//
#include <hip/hip_runtime.h>
#include <hip/hip_bf16.h>
#include <math.h>

// ---------------------------------------------------------------------------
// RGN model: T=700 B=32 H=800 EMB=32 EVO=21 A=60
// f32 in / f32 out; internal bf16 MFMA.
// L0: persistent recurrence, Whh0 LDS-resident (100 WGs).
// L1: ONE persistent kernel, 256 WGs: 100 recurrence WGs (Whh1 LDS-resident,
//     c in registers) + 156 gemm WGs producing xg = Wih1*h0 + b1 one chunk
//     ahead into a 2-slot ring (flag handshake; rec reads xg via L2-bypass
//     atomics since slots are reused).
// R5 changes (post-mortem of R3/R4: VGPR=68 both rounds -> compiler keeps
// sinking the register prefetch to its consume point; hints don't work):
//   * gemm: h0 prefetch now via INLINE-ASM global_load_dwordx4 (volatile ->
//     cannot be sunk; dest regs forced live across the MFMA chain). One
//     address VGPR pair + offset: immediates. Explicit s_waitcnt vmcnt(0)
//     at the consume point before the staging ds_writes.
//   * everything else identical to R4 (rec lgkm-only barriers kept; l0
//     untouched as control). Numerics bit-identical.
// ---------------------------------------------------------------------------

typedef unsigned int u32;
typedef unsigned long long u64;
typedef __bf16 bf16x8 __attribute__((ext_vector_type(8)));
typedef float  f32x4  __attribute__((ext_vector_type(4)));

#define TT 700
#define BT 32
#define HROW 1664          // 800 fwd | 32 pad | 800 bwd | 32 pad
#define CH 50              // chunk length (14 chunks)
#define NCH (TT / CH)
#define SLOT ((size_t)2 * CH * 3200 * 32)      // bf16 elems per xg slot
#define LDS_L0 (108 * 512 + 102400)   // 157,696 B
#define LDS_L1 (100 * 512 + 102400)   // 153,600 B

__device__ __forceinline__ f32x4 mfma16(bf16x8 a, bf16x8 b, f32x4 c) {
  return __builtin_amdgcn_mfma_f32_16x16x32_bf16(a, b, c, 0, 0, 0);
}
__device__ __forceinline__ float sigf(float x) { return 1.f / (1.f + __expf(-x)); }

#define ALOAD(p)    __hip_atomic_load((p), __ATOMIC_RELAXED, __HIP_MEMORY_SCOPE_AGENT)
#define ASTORE(p,v) __hip_atomic_store((p), (v), __ATOMIC_RELAXED, __HIP_MEMORY_SCOPE_AGENT)

// LDS-only workgroup barrier: does NOT drain vmcnt, so global loads issued
// before it stay in flight (T4 counted-wait principle). Safe wherever the
// barrier only orders LDS traffic.
__device__ __forceinline__ void lds_barrier() {
  asm volatile("s_waitcnt lgkmcnt(0)" ::: "memory");
  __builtin_amdgcn_s_barrier();
}

// Pinned 16B global load: volatile asm -> issued exactly here, dest register
// stays live until the explicit vmcnt wait at the consume point.
#define GLOAD(dst, p, OFF)                                          \
  asm volatile("global_load_dwordx4 %0, %1, off offset:" #OFF      \
               : "=v"(dst) : "v"(p) : "memory")

__device__ __forceinline__ bf16x8 cvt8(f32x4 a, f32x4 b) {
  bf16x8 r;
  r[0] = (__bf16)a[0]; r[1] = (__bf16)a[1]; r[2] = (__bf16)a[2]; r[3] = (__bf16)a[3];
  r[4] = (__bf16)b[0]; r[5] = (__bf16)b[1]; r[6] = (__bf16)b[2]; r[7] = (__bf16)b[3];
  return r;
}

// ---------------- pack / init kernels ----------------
__global__ void pack_wx0_kernel(const float* Wih0f, const float* Wih0b, __bf16* wx0) {
  int idx = blockIdx.x * 256 + threadIdx.x;      // 2*3200*64 exact
  if (idx >= 2 * 3200 * 64) return;
  int d = idx / (3200 * 64);
  int r = (idx / 64) % 3200;
  int k = idx % 64;
  const float* W = d ? Wih0b : Wih0f;
  wx0[idx] = (k < 53) ? (__bf16)W[(size_t)r * 53 + k] : (__bf16)0.f;
}

__global__ void pack_fc_kernel(const float* fcW, __bf16* wfc) {
  int idx = blockIdx.x * 256 + threadIdx.x;
  if (idx >= 64 * 1664) return;
  int a = idx / 1664, k = idx % 1664;
  __bf16 v = (__bf16)0.f;
  if (a < 60 && k < 1653) v = (__bf16)fcW[(size_t)a * 1653 + k];
  wfc[idx] = v;
}

__global__ void xpad_kernel(const int* primary, const float* evo,
                            const float* emb, __bf16* xpad) {
  int idx = blockIdx.x * 256 + threadIdx.x;   // 700*32*64 exact
  int t = idx >> 11;
  int b = (idx >> 6) & 31;
  int k = idx & 63;
  __bf16 v = (__bf16)0.f;
  if (k < 32)      v = (__bf16)emb[primary[t * 32 + b] * 32 + k];
  else if (k < 53) v = (__bf16)evo[((size_t)t * 32 + b) * 21 + (k - 32)];
  xpad[idx] = v;
}

__global__ void small_init_kernel(__bf16* zerobuf, u32* flags,
                                  float* sinA, float* cosA, const float* alpha) {
  int idx = blockIdx.x * 256 + threadIdx.x;
  if (idx < 32 * HROW) zerobuf[idx] = (__bf16)0.f;
  if (idx < 11392) flags[idx] = 0u;   // l0: 100 lines; l1: 256 lines (x32 u32)
  int j = idx - 32 * HROW;
  if (j >= 0 && j < 192) {
    if (j < 180) {
      float v = alpha[j];
      sinA[j] = sinf(v);
      cosA[j] = cosf(v);
    } else { sinA[j] = 0.f; cosA[j] = 0.f; }
  }
}

// ---------------- flag helpers ----------------
__device__ __forceinline__ void wait_lines(u32* flags, int base, int count,
                                           unsigned gen) {
  const int tid = threadIdx.x;
  if (tid < 64) {
    int spin = 0;
    for (;;) {
      bool ok = true;
      for (int j = tid; j < count; j += 64)
        ok = ok && (ALOAD(flags + (size_t)(base + j) * 32) >= gen);
      if (__popcll(__ballot(ok)) == 64) break;
      if (++spin > 24) __builtin_amdgcn_s_sleep(1);
    }
  }
  __syncthreads();
}

__device__ __forceinline__ void rec_barrier(u32* flags, unsigned gen,
                                            int base, int count) {
  asm volatile("s_waitcnt vmcnt(0)" ::: "memory");
  __syncthreads();
  if (threadIdx.x == 0) ASTORE(flags + (size_t)blockIdx.x * 32, gen);
  wait_lines(flags, base, count, gen);
}

// ---------------- L0 persistent recurrence ----------------
struct L0Args {
  const __bf16 *xpad, *wx0, *zero;
  const float *Whh0f, *Whh0b, *b0f, *b0b;
  __bf16* h0;
  u32* flags;
};

__global__ __launch_bounds__(256, 1) void lstm_l0(L0Args A) {
  extern __shared__ __bf16 u2[];
  const int wg = blockIdx.x, d = wg / 50, u0 = (wg % 50) * 16;
  const int tid = threadIdx.x, w = tid >> 6, l = tid & 63;
  const int nidx = l & 15, q = l >> 4, bL = l & 31, gl = l >> 5;
  const int dcol = d * 832;
  const int row = w * 800 + u0 + nidx;
  const float bias_n = (d ? A.b0b : A.b0f)[row];
  const float* wrf = (d ? A.Whh0b : A.Whh0f) + (size_t)row * 800 + q * 8;
  __bf16* wlds = u2 + 108 * 256;
  float* g_lds = (float*)u2;
  const int bb = tid >> 3, up = tid & 7;

#pragma unroll
  for (int sl = 0; sl < 25; ++sl) {
    f32x4 wa = *(const f32x4*)(wrf + sl * 32);
    f32x4 wb = *(const f32x4*)(wrf + sl * 32 + 4);
    *(bf16x8*)(wlds + ((size_t)(w * 25 + sl) * 64 + l) * 8) = cvt8(wa, wb);
  }
  const __bf16* wx_row = A.wx0 + (size_t)d * 3200 * 64 + (size_t)row * 64 + q * 8;
  bf16x8 wx_r0 = *(const bf16x8*)wx_row;
  bf16x8 wx_r1 = *(const bf16x8*)(wx_row + 32);
  __syncthreads();

  float cA = 0.f, cB = 0.f;
#pragma unroll 1
  for (int s = 0; s < TT; ++s) {
    const int tt = d ? (TT - 1 - s) : s;
    const __bf16* hprev =
        (s == 0) ? A.zero : (A.h0 + (size_t)(d ? tt + 1 : tt - 1) * (BT * HROW));

    bf16x8 hreg[13];
    const __bf16* hsrc = hprev + (size_t)bL * HROW + dcol;
#pragma unroll
    for (int i = 0; i < 12; ++i)
      hreg[i] = *(const bf16x8*)(hsrc + (i * 8 + w * 2 + gl) * 8);
    if (w < 2) hreg[12] = *(const bf16x8*)(hsrc + (96 + w * 2 + gl) * 8);
    bf16x8 xv = *(const bf16x8*)(A.xpad + ((size_t)tt * BT + bL) * 64 + (tid >> 5) * 8);

#pragma unroll
    for (int i = 0; i < 12; ++i)
      *(bf16x8*)(u2 + (size_t)(i * 8 + w * 2 + gl) * 256 + bL * 8) = hreg[i];
    if (w < 2)
      *(bf16x8*)(u2 + (size_t)(96 + w * 2 + gl) * 256 + bL * 8) = hreg[12];
    *(bf16x8*)(u2 + (size_t)(100 + (tid >> 5)) * 256 + bL * 8) = xv;
    __syncthreads();

    f32x4 acc0 = {0.f, 0.f, 0.f, 0.f}, acc1 = {0.f, 0.f, 0.f, 0.f};
#pragma unroll
    for (int sl = 0; sl < 27; ++sl) {
      bf16x8 bfr;
      if (sl < 25)
        bfr = *(const bf16x8*)(wlds + ((size_t)(w * 25 + sl) * 64 + l) * 8);
      else
        bfr = (sl == 25) ? wx_r0 : wx_r1;
      const __bf16* ab = u2 + (size_t)(sl * 4 + q) * 256 + nidx * 8;
      bf16x8 a0 = *(const bf16x8*)ab;
      bf16x8 a1 = *(const bf16x8*)(ab + 128);
      acc0 = mfma16(a0, bfr, acc0);
      acc1 = mfma16(a1, bfr, acc1);
    }
    __syncthreads();

#pragma unroll
    for (int r = 0; r < 4; ++r) {
      g_lds[w * 512 + (q * 4 + r) * 16 + nidx]      = acc0[r] + bias_n;
      g_lds[w * 512 + (16 + q * 4 + r) * 16 + nidx] = acc1[r] + bias_n;
    }
    __syncthreads();

    {
      const int uA = 2 * up, uB = uA + 1;
      float iA = g_lds[0 * 512 + bb * 16 + uA], fA = g_lds[1 * 512 + bb * 16 + uA];
      float gA = g_lds[2 * 512 + bb * 16 + uA], oA = g_lds[3 * 512 + bb * 16 + uA];
      cA = sigf(fA) * cA + sigf(iA) * tanhf(gA);
      float hA = sigf(oA) * tanhf(cA);
      float iB = g_lds[0 * 512 + bb * 16 + uB], fB = g_lds[1 * 512 + bb * 16 + uB];
      float gB = g_lds[2 * 512 + bb * 16 + uB], oB = g_lds[3 * 512 + bb * 16 + uB];
      cB = sigf(fB) * cB + sigf(iB) * tanhf(gB);
      float hB = sigf(oB) * tanhf(cB);
      union { u32 u; __bf16 h2[2]; } pk;
      pk.h2[0] = (__bf16)hA;
      pk.h2[1] = (__bf16)hB;
      ASTORE((u32*)(A.h0 + ((size_t)tt * BT + bb) * HROW + dcol + u0 + uA), pk.u);
    }

    if (s < TT - 1) rec_barrier(A.flags, (unsigned)(s + 1), d * 50, 50);
  }
}

// ---------------- L1: persistent rec (100 WGs) + xg gemm (156 WGs) ----------
struct L1Args {
  const __bf16 *h0, *zero;
  const float *Whh1f, *Whh1b, *Wih1f, *Wih1b, *b1f, *b1b;
  __bf16 *h1, *xg;
  u32* flags;     // lines 0..99: rec; 100..255: gemm
};

__global__ __launch_bounds__(256, 1) void lstm_l1(L1Args A) {
  extern __shared__ __bf16 u2[];
  const int tid = threadIdx.x, w = tid >> 6, l = tid & 63;
  const int nidx = l & 15, q = l >> 4, bL = l & 31, gl = l >> 5;
  __bf16* wlds = u2 + 100 * 256;

  if (blockIdx.x < 100) {
    // ---------------- recurrence consumer ----------------
    const int wg = blockIdx.x, d = wg / 50, u0 = (wg % 50) * 16;
    const int dcol = d * 832;
    const int row = w * 800 + u0 + nidx;
    float* g_lds = (float*)u2;
    const int bb = tid >> 3, up = tid & 7;
    {
      const float* wrf = (d ? A.Whh1b : A.Whh1f) + (size_t)row * 800 + q * 8;
#pragma unroll
      for (int sl = 0; sl < 25; ++sl) {
        f32x4 wa = *(const f32x4*)(wrf + sl * 32);
        f32x4 wb = *(const f32x4*)(wrf + sl * 32 + 4);
        *(bf16x8*)(wlds + ((size_t)(w * 25 + sl) * 64 + l) * 8) = cvt8(wa, wb);
      }
    }
    __syncthreads();
    float cA = 0.f, cB = 0.f;

    for (int k = 0; k < NCH; ++k) {
      wait_lines(A.flags, 100, 156, (unsigned)(k + 1));   // xg chunk k ready
      const __bf16* buf = A.xg + (size_t)(k & 1) * SLOT;
      // preload xg for si=0 (L2-bypass: slots are reused -> cached reads unsafe)
      const u64* xga0 = (const u64*)(buf + ((size_t)(d * CH) * 3200 + row) * 32 + q * 4);
      u64 x0 = ALOAD(xga0);
      u64 x1 = ALOAD(xga0 + 4);
#pragma unroll 1
      for (int si = 0; si < CH; ++si) {
        const int s = k * CH + si;
        const int tt = d ? (TT - 1 - s) : s;
        const __bf16* hprev =
            (s == 0) ? A.zero
                     : (A.h1 + (size_t)(d ? tt + 1 : tt - 1) * (BT * HROW));

        u64 cx0 = x0, cx1 = x1;
        if (si + 1 < CH) {
          const u64* xgn = (const u64*)(buf +
              ((size_t)(d * CH + si + 1) * 3200 + row) * 32 + q * 4);
          x0 = ALOAD(xgn);
          x1 = ALOAD(xgn + 4);
        }

        bf16x8 hreg[13];
        const __bf16* hsrc = hprev + (size_t)bL * HROW + dcol;
#pragma unroll
        for (int i = 0; i < 12; ++i)
          hreg[i] = *(const bf16x8*)(hsrc + (i * 8 + w * 2 + gl) * 8);
        if (w < 2) hreg[12] = *(const bf16x8*)(hsrc + (96 + w * 2 + gl) * 8);

        union { u64 u; __bf16 h[4]; } ux0, ux1;
        ux0.u = cx0; ux1.u = cx1;
        f32x4 acc0 = {(float)ux0.h[0], (float)ux0.h[1],
                      (float)ux0.h[2], (float)ux0.h[3]};
        f32x4 acc1 = {(float)ux1.h[0], (float)ux1.h[1],
                      (float)ux1.h[2], (float)ux1.h[3]};

#pragma unroll
        for (int i = 0; i < 12; ++i)
          *(bf16x8*)(u2 + (size_t)(i * 8 + w * 2 + gl) * 256 + bL * 8) = hreg[i];
        if (w < 2)
          *(bf16x8*)(u2 + (size_t)(96 + w * 2 + gl) * 256 + bL * 8) = hreg[12];
        lds_barrier();   // LDS-only: keeps xg prefetch in flight

#pragma unroll
        for (int sl = 0; sl < 25; ++sl) {
          bf16x8 bfr = *(const bf16x8*)(wlds + ((size_t)(w * 25 + sl) * 64 + l) * 8);
          const __bf16* ab = u2 + (size_t)(sl * 4 + q) * 256 + nidx * 8;
          bf16x8 a0 = *(const bf16x8*)ab;
          bf16x8 a1 = *(const bf16x8*)(ab + 128);
          acc0 = mfma16(a0, bfr, acc0);
          acc1 = mfma16(a1, bfr, acc1);
        }
        lds_barrier();

#pragma unroll
        for (int r = 0; r < 4; ++r) {
          g_lds[w * 512 + (q * 4 + r) * 16 + nidx]      = acc0[r];
          g_lds[w * 512 + (16 + q * 4 + r) * 16 + nidx] = acc1[r];
        }
        lds_barrier();

        {
          const int uA = 2 * up, uB = uA + 1;
          float iA = g_lds[0 * 512 + bb * 16 + uA], fA = g_lds[1 * 512 + bb * 16 + uA];
          float gA = g_lds[2 * 512 + bb * 16 + uA], oA = g_lds[3 * 512 + bb * 16 + uA];
          cA = sigf(fA) * cA + sigf(iA) * tanhf(gA);
          float hA = sigf(oA) * tanhf(cA);
          float iB = g_lds[0 * 512 + bb * 16 + uB], fB = g_lds[1 * 512 + bb * 16 + uB];
          float gB = g_lds[2 * 512 + bb * 16 + uB], oB = g_lds[3 * 512 + bb * 16 + uB];
          cB = sigf(fB) * cB + sigf(iB) * tanhf(gB);
          float hB = sigf(oB) * tanhf(cB);
          union { u32 u; __bf16 h2[2]; } pk;
          pk.h2[0] = (__bf16)hA;
          pk.h2[1] = (__bf16)hB;
          ASTORE((u32*)(A.h1 + ((size_t)tt * BT + bb) * HROW + dcol + u0 + uA), pk.u);
        }

        if (s < TT - 1) rec_barrier(A.flags, (unsigned)(s + 1), 0 + d * 50, 50);
      }
    }
  } else {
    // ---------------- xg producer: 156 WGs, 400 half-tile units/chunk ------
    // Slot s: u = u_begin + s/50, th = u&1, tloc = th*25 + (s%50)/2,
    // pass = s&1. pre[] = NEXT slot's h0 rows, loaded via pinned inline-asm
    // global_load_dwordx4 issued right after barrier A; consumed at the next
    // slot's staging behind an explicit s_waitcnt vmcnt(0). The lgkm-only
    // barriers keep the loads in flight across the whole MFMA chain.
    const int g = blockIdx.x - 100;
    const int u_begin = (g * 400) / 156;
    const int u_end   = ((g + 1) * 400) / 156;
    const int nslots  = (u_end - u_begin) * 50;
    const int rh = w >> 1, bh = w & 1;
    const int csub = (w * 2 + gl) * 8;   // per-lane subtile column offset

    bf16x8 pre[13];
    f32x4 acc = {0.f, 0.f, 0.f, 0.f};
    int cur_tl = -1;
    float bn = 0.f;
    int rr = 0;

    for (int k = 0; k < NCH; ++k) {
      // slot (k&1) reused by chunk k-2's reader: wait until rec done chunk k-2
      if (k >= 2) wait_lines(A.flags, 0, 100, (unsigned)((k - 1) * CH));
      __bf16* buf = A.xg + (size_t)(k & 1) * SLOT;

      // cold prefetch for slot 0 of this chunk (u_begin, first tloc, pass 0)
      {
        const int th0 = u_begin & 1;
        const int dir0 = (u_begin >> 1) / 100;
        const int tloc0 = th0 * 25;
        const int t0 = dir0 ? (TT - 1 - k * CH - tloc0) : (k * CH + tloc0);
        const __bf16* pb = A.h0 + ((size_t)t0 * BT + bL) * HROW + csub;
        GLOAD(pre[0],  pb, 0);    GLOAD(pre[1],  pb, 128);
        GLOAD(pre[2],  pb, 256);  GLOAD(pre[3],  pb, 384);
        GLOAD(pre[4],  pb, 512);  GLOAD(pre[5],  pb, 640);
        GLOAD(pre[6],  pb, 768);  GLOAD(pre[7],  pb, 896);
        GLOAD(pre[8],  pb, 1024); GLOAD(pre[9],  pb, 1152);
        GLOAD(pre[10], pb, 1280); GLOAD(pre[11], pb, 1408);
        if (w < 2) GLOAD(pre[12], pb, 1536);
      }

#pragma unroll 1
      for (int s = 0; s < nslots; ++s) {
        const int u = u_begin + s / 50;
        const int r = s % 50;
        const int tl = u >> 1, th = u & 1;
        const int tloc = th * 25 + (r >> 1);
        const int pass = r & 1;
        const int dir = tl / 100, rt = tl % 100;
        const int rbase = rt * 32;

        if (tl != cur_tl) {               // new W tile (only hit at pass==0)
          cur_tl = tl;
          const float* W = dir ? A.Wih1b : A.Wih1f;
          __syncthreads();   // protect wlds from previous tile's MFMAs
          for (int i = w * 25; i < w * 25 + 25; ++i) {
            const int rhh = i / 50, sl = i % 50;
            const int rrr = rbase + rhh * 16 + nidx;
            const float* wp = W + (size_t)rrr * 1600 + sl * 32 + q * 8;
            f32x4 wa = *(const f32x4*)wp;
            f32x4 wb = *(const f32x4*)(wp + 4);
            *(bf16x8*)(wlds + ((size_t)i * 64 + l) * 8) = cvt8(wa, wb);
          }
          __syncthreads();
          rr = rbase + rh * 16 + nidx;
          bn = (dir ? A.b1b : A.b1f)[rr];
        }

        // consume the prefetch: wait it, then stage into u2
        asm volatile("s_waitcnt vmcnt(0)" ::: "memory");
#pragma unroll
        for (int i = 0; i < 12; ++i)
          *(bf16x8*)(u2 + (size_t)(i * 8 + w * 2 + gl) * 256 + bL * 8) = pre[i];
        if (w < 2)
          *(bf16x8*)(u2 + (size_t)(96 + w * 2 + gl) * 256 + bL * 8) = pre[12];
        lds_barrier();   // A: staging visible; no vmcnt drain

        // issue NEXT slot's loads (pinned); latency hides under MFMA chain
        if (s + 1 < nslots) {
          const int s2 = s + 1;
          const int un = u_begin + s2 / 50;
          const int r2 = s2 % 50;
          const int thn = un & 1;
          const int tlocn = thn * 25 + (r2 >> 1);
          const int passn = r2 & 1;
          const int dirn = (un >> 1) / 100;
          const int tn = dirn ? (TT - 1 - k * CH - tlocn) : (k * CH + tlocn);
          const __bf16* pb = A.h0 + ((size_t)tn * BT + bL) * HROW +
                             passn * 832 + csub;
          GLOAD(pre[0],  pb, 0);    GLOAD(pre[1],  pb, 128);
          GLOAD(pre[2],  pb, 256);  GLOAD(pre[3],  pb, 384);
          GLOAD(pre[4],  pb, 512);  GLOAD(pre[5],  pb, 640);
          GLOAD(pre[6],  pb, 768);  GLOAD(pre[7],  pb, 896);
          GLOAD(pre[8],  pb, 1024); GLOAD(pre[9],  pb, 1152);
          GLOAD(pre[10], pb, 1280); GLOAD(pre[11], pb, 1408);
          if (w < 2) GLOAD(pre[12], pb, 1536);
        }

        if (pass == 0) acc = f32x4{0.f, 0.f, 0.f, 0.f};
#pragma unroll
        for (int sl = 0; sl < 25; ++sl) {
          bf16x8 b = *(const bf16x8*)(wlds +
              ((size_t)(rh * 50 + pass * 25 + sl) * 64 + l) * 8);
          bf16x8 a = *(const bf16x8*)(u2 +
              (size_t)(sl * 4 + q) * 256 + (bh * 16 + nidx) * 8);
          acc = mfma16(a, b, acc);
        }
        lds_barrier();   // B: reads done; prefetch stays in flight

        if (pass == 1) {
          union { u64 u; __bf16 h[4]; } pv;
#pragma unroll
          for (int r2 = 0; r2 < 4; ++r2) pv.h[r2] = (__bf16)(acc[r2] + bn);
          ASTORE((u64*)(buf + ((size_t)(dir * CH + tloc) * 3200 + rr) * 32 +
                        bh * 16 + q * 4), pv.u);
        }
      }
      asm volatile("s_waitcnt vmcnt(0)" ::: "memory");   // xg at coherence pt
      __syncthreads();
      if (tid == 0) ASTORE(A.flags + (size_t)(100 + g) * 32, (unsigned)(k + 1));
    }
  }
}

// ---------------- FC + softmax + dihedral -> points ----------------
__global__ __launch_bounds__(256) void fc_kernel(
    const __bf16* __restrict__ h1, const __bf16* __restrict__ xpad,
    const __bf16* __restrict__ wfc, const float* __restrict__ fcb,
    const float* __restrict__ sinA, const float* __restrict__ cosA,
    float* __restrict__ pts) {
  __shared__ float lg[32 * 64];
  const int t = blockIdx.x, tid = threadIdx.x;
  const int wave = tid >> 6, lane = tid & 63, nidx = lane & 15, q = lane >> 4;
  const int a_col = wave * 16 + nidx;
  const __bf16* wrow = wfc + (size_t)a_col * 1664 + q * 8;
  const __bf16* h1row = h1 + (size_t)t * BT * HROW;
  const __bf16* xrow  = xpad + (size_t)t * BT * 64;
  f32x4 acc0 = {0.f, 0.f, 0.f, 0.f}, acc1 = {0.f, 0.f, 0.f, 0.f};
#pragma unroll
  for (int sl = 0; sl < 52; ++sl) {
    const int k = sl * 32 + q * 8;
    bf16x8 a0, a1;
    if (sl < 50) {
      const int kp = (sl < 25) ? k : (k + 32);
      a0 = *(const bf16x8*)(h1row + (size_t)nidx * HROW + kp);
      a1 = *(const bf16x8*)(h1row + (size_t)(16 + nidx) * HROW + kp);
    } else {
      a0 = *(const bf16x8*)(xrow + nidx * 64 + (k - 1600));
      a1 = *(const bf16x8*)(xrow + (16 + nidx) * 64 + (k - 1600));
    }
    bf16x8 bfr = *(const bf16x8*)(wrow + sl * 32);
    acc0 = mfma16(a0, bfr, acc0);
    acc1 = mfma16(a1, bfr, acc1);
  }
  const float bn = (a_col < 60) ? fcb[a_col] : -1e30f;
#pragma unroll
  for (int r = 0; r < 4; ++r) {
    lg[(q * 4 + r) * 64 + a_col]      = acc0[r] + bn;
    lg[(16 + q * 4 + r) * 64 + a_col] = acc1[r] + bn;
  }
  __syncthreads();

  const int b = tid >> 3, j = tid & 7;
  float v[8];
  float m = -1e30f;
#pragma unroll
  for (int k2 = 0; k2 < 8; ++k2) {
    v[k2] = lg[b * 64 + j + 8 * k2];
    m = fmaxf(m, v[k2]);
  }
  m = fmaxf(m, __shfl_xor(m, 1, 8));
  m = fmaxf(m, __shfl_xor(m, 2, 8));
  m = fmaxf(m, __shfl_xor(m, 4, 8));
  float s = 0.f;
#pragma unroll
  for (int k2 = 0; k2 < 8; ++k2) { v[k2] = __expf(v[k2] - m); s += v[k2]; }
  s += __shfl_xor(s, 1, 8);
  s += __shfl_xor(s, 2, 8);
  s += __shfl_xor(s, 4, 8);
  const float inv = 1.f / s;
  float ps[3] = {0.f, 0.f, 0.f}, pc[3] = {0.f, 0.f, 0.f};
#pragma unroll
  for (int k2 = 0; k2 < 8; ++k2) {
    const int a = j + 8 * k2;
    const float p = v[k2] * inv;
#pragma unroll
    for (int c = 0; c < 3; ++c) {
      ps[c] += p * sinA[a * 3 + c];
      pc[c] += p * cosA[a * 3 + c];
    }
  }
#pragma unroll
  for (int c = 0; c < 3; ++c) {
    ps[c] += __shfl_xor(ps[c], 1, 8);
    ps[c] += __shfl_xor(ps[c], 2, 8);
    ps[c] += __shfl_xor(ps[c], 4, 8);
    pc[c] += __shfl_xor(pc[c], 1, 8);
    pc[c] += __shfl_xor(pc[c], 2, 8);
    pc[c] += __shfl_xor(pc[c], 4, 8);
  }
  if (j == 0) {
    const float BL[3] = {145.801f, 152.326f, 132.868f};
    const float BA[3] = {2.124f, 1.941f, 2.028f};
#pragma unroll
    for (int c = 0; c < 3; ++c) {
      const float ang = 3.14159265358979323846f - BA[c];
      const float rct = BL[c] * cosf(ang), rst = BL[c] * sinf(ang);
      const float dih = atan2f(ps[c], pc[c]);
      float* o = pts + ((size_t)(3 * t + c) * BT + b) * 3;
      o[0] = rct;
      o[1] = cosf(dih) * rst;
      o[2] = sinf(dih) * rst;
    }
  }
}

// ---------------- sequential NeRF extension ----------------
__global__ void nerf_kernel(const float* __restrict__ pts, float* __restrict__ out) {
  const int b = threadIdx.x;
  if (b >= 32) return;
  float ax = -0.70710678f, ay = 1.22474487f, az = 0.f;
  float bx = -1.41421356f, by = 0.f, bz = 0.f;
  float cx = 0.f, cy = 0.f, cz = 0.f;
#pragma unroll 4
  for (int i = 0; i < 3 * TT; ++i) {
    const float* p = pts + ((size_t)i * BT + b) * 3;
    const float p0 = p[0], p1 = p[1], p2 = p[2];
    float ux = cx - bx, uy = cy - by, uz = cz - bz;
    const float ri = rsqrtf(ux * ux + uy * uy + uz * uz + 1e-12f);
    ux *= ri; uy *= ri; uz *= ri;
    const float wx = bx - ax, wy = by - ay, wz = bz - az;
    float nx = wy * uz - wz * uy, ny = wz * ux - wx * uz, nz = wx * uy - wy * ux;
    const float rn = rsqrtf(nx * nx + ny * ny + nz * nz + 1e-12f);
    nx *= rn; ny *= rn; nz *= rn;
    const float mx = ny * uz - nz * uy, my = nz * ux - nx * uz, mz = nx * uy - ny * ux;
    const float ox = cx + p0 * ux + p1 * mx + p2 * nx;
    const float oy = cy + p0 * uy + p1 * my + p2 * ny;
    const float oz = cz + p0 * uz + p1 * mz + p2 * nz;
    out[((size_t)i * BT + b) * 3 + 0] = ox;
    out[((size_t)i * BT + b) * 3 + 1] = oy;
    out[((size_t)i * BT + b) * 3 + 2] = oz;
    ax = bx; ay = by; az = bz;
    bx = cx; by = cy; bz = cz;
    cx = ox; cy = oy; cz = oz;
  }
}

// ---------------- launch ----------------
extern "C" void kernel_launch(void* const* d_in, const int* in_sizes, int n_in,
                              void* d_out, int out_size, void* d_ws, size_t ws_size,
                              hipStream_t stream) {
  (void)in_sizes; (void)n_in; (void)out_size;
  const int*   primary = (const int*)d_in[0];
  const float* evo     = (const float*)d_in[1];
  const float* emb     = (const float*)d_in[3];
  const float* Wih0f   = (const float*)d_in[4];
  const float* Whh0f   = (const float*)d_in[5];
  const float* b0f     = (const float*)d_in[6];
  const float* Wih0b   = (const float*)d_in[7];
  const float* Whh0b   = (const float*)d_in[8];
  const float* b0b     = (const float*)d_in[9];
  const float* Wih1f   = (const float*)d_in[10];
  const float* Whh1f   = (const float*)d_in[11];
  const float* b1f     = (const float*)d_in[12];
  const float* Wih1b   = (const float*)d_in[13];
  const float* Whh1b   = (const float*)d_in[14];
  const float* b1b     = (const float*)d_in[15];
  const float* fcW     = (const float*)d_in[16];
  const float* fcb     = (const float*)d_in[17];
  const float* alpha   = (const float*)d_in[18];

  char* ws = (char*)d_ws;
  size_t off = 0;
  auto take = [&](size_t n) -> void* {
    void* p = ws + off;
    off += (n + 511) & ~(size_t)511;
    return p;
  };
  __bf16* xpad = (__bf16*)take((size_t)TT * BT * 64 * 2);
  __bf16* zb   = (__bf16*)take((size_t)BT * HROW * 2);
  __bf16* wx0  = (__bf16*)take((size_t)2 * 3200 * 64 * 2);
  __bf16* wfc  = (__bf16*)take((size_t)64 * 1664 * 2);
  float*  sinA = (float*)take(192 * 4);
  float*  cosA = (float*)take(192 * 4);
  float*  pts  = (float*)take((size_t)3 * TT * BT * 3 * 4);
  u32*    flags0 = (u32*)take(11392 * 4);      // l0: 100 lines; l1: 256 lines
  u32*    flags1 = flags0 + 3200;
  __bf16* xg   = (__bf16*)take(2 * SLOT * 2);  // 41 MB, 2-slot ring
  __bf16* h0   = (__bf16*)take((size_t)TT * BT * HROW * 2);
  __bf16* h1   = (__bf16*)take((size_t)TT * BT * HROW * 2);
  if (off > ws_size) return;  // failure signature: absmax == max|ref| == 233472

  static int lds_cfg = 0;
  if (!lds_cfg) {
    hipFuncSetAttribute((const void*)lstm_l0,
                        hipFuncAttributeMaxDynamicSharedMemorySize, LDS_L0);
    hipFuncSetAttribute((const void*)lstm_l1,
                        hipFuncAttributeMaxDynamicSharedMemorySize, LDS_L1);
    lds_cfg = 1;
  }

  pack_wx0_kernel<<<1600, 256, 0, stream>>>(Wih0f, Wih0b, wx0);
  pack_fc_kernel<<<(64 * 1664 + 255) / 256, 256, 0, stream>>>(fcW, wfc);
  xpad_kernel<<<(TT * BT * 64) / 256, 256, 0, stream>>>(primary, evo, emb, xpad);
  small_init_kernel<<<209, 256, 0, stream>>>(zb, flags0, sinA, cosA, alpha);

  L0Args a0;
  a0.xpad = xpad; a0.wx0 = wx0; a0.zero = zb;
  a0.Whh0f = Whh0f; a0.Whh0b = Whh0b; a0.b0f = b0f; a0.b0b = b0b;
  a0.h0 = h0; a0.flags = flags0;
  lstm_l0<<<100, 256, LDS_L0, stream>>>(a0);

  L1Args a1;
  a1.h0 = h0; a1.zero = zb;
  a1.Whh1f = Whh1f; a1.Whh1b = Whh1b;
  a1.Wih1f = Wih1f; a1.Wih1b = Wih1b;
  a1.b1f = b1f; a1.b1b = b1b;
  a1.h1 = h1; a1.xg = xg; a1.flags = flags1;
  lstm_l1<<<256, 256, LDS_L1, stream>>>(a1);

  fc_kernel<<<TT, 256, 0, stream>>>(h1, xpad, wfc, fcb, sinA, cosA, pts);
  nerf_kernel<<<1, 64, 0, stream>>>(pts, (float*)d_out);
}

// Round 6
// 9199.989 us; speedup vs baseline: 1.0089x; 1.0089x over previous
//
#include <hip/hip_runtime.h>
#include <hip/hip_bf16.h>
#include <math.h>

// ---------------------------------------------------------------------------
// RGN model: T=700 B=32 H=800 EMB=32 EVO=21 A=60
// f32 in / f32 out; internal bf16 MFMA.
// L0: persistent recurrence, Whh0 LDS-resident (100 WGs).
// L1: ONE persistent kernel, 256 WGs: 100 recurrence WGs (Whh1 LDS-resident,
//     c in registers) + 156 gemm WGs producing xg = Wih1*h0 + b1 one chunk
//     ahead into a 2-slot ring (flag handshake; rec reads xg via L2-bypass
//     atomics since slots are reused).
// R6 changes (post-mortem R5: real prefetch (VGPR 76) changed nothing ->
// gemm step is work/stall-bound, not latency-bound; rec path never touched):
//   * rec (l0 + l1): gate-interleaved W-row assignment. N-slot n holds W row
//     (n&3)*800 + u0 + 4w + (n>>2), so each wave computes all 4 gates for 4
//     units. Gate gather = in-register 4x4 lane-quad transpose (shfl_xor),
//     killing the g_lds round trip and 2 of 3 intra-step barriers. Same dot
//     products -> bit-identical numerics. h stored as packed u32 via one
//     shfl_xor(.,4) pair (half the lanes store).
//   * gemm: reverted to R4 form (best measured; R5 asm prefetch was -4%).
// ---------------------------------------------------------------------------

typedef unsigned int u32;
typedef unsigned long long u64;
typedef __bf16 bf16x8 __attribute__((ext_vector_type(8)));
typedef float  f32x4  __attribute__((ext_vector_type(4)));

#define TT 700
#define BT 32
#define HROW 1664          // 800 fwd | 32 pad | 800 bwd | 32 pad
#define CH 50              // chunk length (14 chunks)
#define NCH (TT / CH)
#define SLOT ((size_t)2 * CH * 3200 * 32)      // bf16 elems per xg slot
#define LDS_L0 (108 * 512 + 102400)   // 157,696 B
#define LDS_L1 (100 * 512 + 102400)   // 153,600 B

__device__ __forceinline__ f32x4 mfma16(bf16x8 a, bf16x8 b, f32x4 c) {
  return __builtin_amdgcn_mfma_f32_16x16x32_bf16(a, b, c, 0, 0, 0);
}
__device__ __forceinline__ float sigf(float x) { return 1.f / (1.f + __expf(-x)); }

#define ALOAD(p)    __hip_atomic_load((p), __ATOMIC_RELAXED, __HIP_MEMORY_SCOPE_AGENT)
#define ASTORE(p,v) __hip_atomic_store((p), (v), __ATOMIC_RELAXED, __HIP_MEMORY_SCOPE_AGENT)

// LDS-only workgroup barrier: does NOT drain vmcnt, so global loads issued
// before it stay in flight.
__device__ __forceinline__ void lds_barrier() {
  asm volatile("s_waitcnt lgkmcnt(0)" ::: "memory");
  __builtin_amdgcn_s_barrier();
}

__device__ __forceinline__ bf16x8 cvt8(f32x4 a, f32x4 b) {
  bf16x8 r;
  r[0] = (__bf16)a[0]; r[1] = (__bf16)a[1]; r[2] = (__bf16)a[2]; r[3] = (__bf16)a[3];
  r[4] = (__bf16)b[0]; r[5] = (__bf16)b[1]; r[6] = (__bf16)b[2]; r[7] = (__bf16)b[3];
  return r;
}

// 4x4 transpose across lane quads: input in[r] = (this lane's gate) for
// batch-sub r; output out[g] = gate g for batch-sub (lane&3).
// Lane bits 0-1 <-> reg index bits 0-1.
#define QUAD_TRANSPOSE(l_, a0, a1, a2, a3, o0, o1, o2, o3)                   \
  {                                                                          \
    float s0 = __shfl_xor(a0, 1), s1 = __shfl_xor(a1, 1);                    \
    float s2 = __shfl_xor(a2, 1), s3 = __shfl_xor(a3, 1);                    \
    const bool e1 = ((l_) & 1) == 0;                                         \
    float n0 = e1 ? a0 : s1, n1 = e1 ? s0 : a1;                              \
    float n2 = e1 ? a2 : s3, n3 = e1 ? s2 : a3;                              \
    float t0 = __shfl_xor(n0, 2), t1 = __shfl_xor(n1, 2);                    \
    float t2 = __shfl_xor(n2, 2), t3 = __shfl_xor(n3, 2);                    \
    const bool e2 = ((l_) & 2) == 0;                                         \
    o0 = e2 ? n0 : t2; o1 = e2 ? n1 : t3;                                    \
    o2 = e2 ? t0 : n2; o3 = e2 ? t1 : n3;                                    \
  }

// ---------------- pack / init kernels ----------------
__global__ void pack_wx0_kernel(const float* Wih0f, const float* Wih0b, __bf16* wx0) {
  int idx = blockIdx.x * 256 + threadIdx.x;      // 2*3200*64 exact
  if (idx >= 2 * 3200 * 64) return;
  int d = idx / (3200 * 64);
  int r = (idx / 64) % 3200;
  int k = idx % 64;
  const float* W = d ? Wih0b : Wih0f;
  wx0[idx] = (k < 53) ? (__bf16)W[(size_t)r * 53 + k] : (__bf16)0.f;
}

__global__ void pack_fc_kernel(const float* fcW, __bf16* wfc) {
  int idx = blockIdx.x * 256 + threadIdx.x;
  if (idx >= 64 * 1664) return;
  int a = idx / 1664, k = idx % 1664;
  __bf16 v = (__bf16)0.f;
  if (a < 60 && k < 1653) v = (__bf16)fcW[(size_t)a * 1653 + k];
  wfc[idx] = v;
}

__global__ void xpad_kernel(const int* primary, const float* evo,
                            const float* emb, __bf16* xpad) {
  int idx = blockIdx.x * 256 + threadIdx.x;   // 700*32*64 exact
  int t = idx >> 11;
  int b = (idx >> 6) & 31;
  int k = idx & 63;
  __bf16 v = (__bf16)0.f;
  if (k < 32)      v = (__bf16)emb[primary[t * 32 + b] * 32 + k];
  else if (k < 53) v = (__bf16)evo[((size_t)t * 32 + b) * 21 + (k - 32)];
  xpad[idx] = v;
}

__global__ void small_init_kernel(__bf16* zerobuf, u32* flags,
                                  float* sinA, float* cosA, const float* alpha) {
  int idx = blockIdx.x * 256 + threadIdx.x;
  if (idx < 32 * HROW) zerobuf[idx] = (__bf16)0.f;
  if (idx < 11392) flags[idx] = 0u;   // l0: 100 lines; l1: 256 lines (x32 u32)
  int j = idx - 32 * HROW;
  if (j >= 0 && j < 192) {
    if (j < 180) {
      float v = alpha[j];
      sinA[j] = sinf(v);
      cosA[j] = cosf(v);
    } else { sinA[j] = 0.f; cosA[j] = 0.f; }
  }
}

// ---------------- flag helpers ----------------
__device__ __forceinline__ void wait_lines(u32* flags, int base, int count,
                                           unsigned gen) {
  const int tid = threadIdx.x;
  if (tid < 64) {
    int spin = 0;
    for (;;) {
      bool ok = true;
      for (int j = tid; j < count; j += 64)
        ok = ok && (ALOAD(flags + (size_t)(base + j) * 32) >= gen);
      if (__popcll(__ballot(ok)) == 64) break;
      if (++spin > 24) __builtin_amdgcn_s_sleep(1);
    }
  }
  __syncthreads();
}

__device__ __forceinline__ void rec_barrier(u32* flags, unsigned gen,
                                            int base, int count) {
  asm volatile("s_waitcnt vmcnt(0)" ::: "memory");
  __syncthreads();
  if (threadIdx.x == 0) ASTORE(flags + (size_t)blockIdx.x * 32, gen);
  wait_lines(flags, base, count, gen);
}

// ---------------- L0 persistent recurrence ----------------
struct L0Args {
  const __bf16 *xpad, *wx0, *zero;
  const float *Whh0f, *Whh0b, *b0f, *b0b;
  __bf16* h0;
  u32* flags;
};

__global__ __launch_bounds__(256, 1) void lstm_l0(L0Args A) {
  extern __shared__ __bf16 u2[];
  const int wg = blockIdx.x, d = wg / 50, u0 = (wg % 50) * 16;
  const int tid = threadIdx.x, w = tid >> 6, l = tid & 63;
  const int nidx = l & 15, q = l >> 4, bL = l & 31, gl = l >> 5;
  const int dcol = d * 832;
  // gate-interleaved row: N-slot nidx -> gate nidx&3, unit u0+4w+(nidx>>2)
  const int row = (nidx & 3) * 800 + u0 + 4 * w + (nidx >> 2);
  const float bias_n = (d ? A.b0b : A.b0f)[row];
  const float* wrf = (d ? A.Whh0b : A.Whh0f) + (size_t)row * 800 + q * 8;
  __bf16* wlds = u2 + 108 * 256;

#pragma unroll
  for (int sl = 0; sl < 25; ++sl) {
    f32x4 wa = *(const f32x4*)(wrf + sl * 32);
    f32x4 wb = *(const f32x4*)(wrf + sl * 32 + 4);
    *(bf16x8*)(wlds + ((size_t)(w * 25 + sl) * 64 + l) * 8) = cvt8(wa, wb);
  }
  const __bf16* wx_row = A.wx0 + (size_t)d * 3200 * 64 + (size_t)row * 64 + q * 8;
  bf16x8 wx_r0 = *(const bf16x8*)wx_row;
  bf16x8 wx_r1 = *(const bf16x8*)(wx_row + 32);
  __syncthreads();

  float cA = 0.f, cB = 0.f;
#pragma unroll 1
  for (int s = 0; s < TT; ++s) {
    const int tt = d ? (TT - 1 - s) : s;
    const __bf16* hprev =
        (s == 0) ? A.zero : (A.h0 + (size_t)(d ? tt + 1 : tt - 1) * (BT * HROW));

    bf16x8 hreg[13];
    const __bf16* hsrc = hprev + (size_t)bL * HROW + dcol;
#pragma unroll
    for (int i = 0; i < 12; ++i)
      hreg[i] = *(const bf16x8*)(hsrc + (i * 8 + w * 2 + gl) * 8);
    if (w < 2) hreg[12] = *(const bf16x8*)(hsrc + (96 + w * 2 + gl) * 8);
    bf16x8 xv = *(const bf16x8*)(A.xpad + ((size_t)tt * BT + bL) * 64 + (tid >> 5) * 8);

#pragma unroll
    for (int i = 0; i < 12; ++i)
      *(bf16x8*)(u2 + (size_t)(i * 8 + w * 2 + gl) * 256 + bL * 8) = hreg[i];
    if (w < 2)
      *(bf16x8*)(u2 + (size_t)(96 + w * 2 + gl) * 256 + bL * 8) = hreg[12];
    *(bf16x8*)(u2 + (size_t)(100 + (tid >> 5)) * 256 + bL * 8) = xv;
    __syncthreads();

    f32x4 acc0 = {0.f, 0.f, 0.f, 0.f}, acc1 = {0.f, 0.f, 0.f, 0.f};
#pragma unroll
    for (int sl = 0; sl < 27; ++sl) {
      bf16x8 bfr;
      if (sl < 25)
        bfr = *(const bf16x8*)(wlds + ((size_t)(w * 25 + sl) * 64 + l) * 8);
      else
        bfr = (sl == 25) ? wx_r0 : wx_r1;
      const __bf16* ab = u2 + (size_t)(sl * 4 + q) * 256 + nidx * 8;
      bf16x8 a0 = *(const bf16x8*)ab;
      bf16x8 a1 = *(const bf16x8*)(ab + 128);
      acc0 = mfma16(a0, bfr, acc0);
      acc1 = mfma16(a1, bfr, acc1);
    }

    // in-register gate gather: acc0[r] = (own gate) for batch q*4+r.
    {
      float a0 = acc0[0] + bias_n, a1 = acc0[1] + bias_n,
            a2 = acc0[2] + bias_n, a3 = acc0[3] + bias_n;
      float e0 = acc1[0] + bias_n, e1v = acc1[1] + bias_n,
            e2v = acc1[2] + bias_n, e3 = acc1[3] + bias_n;
      float iA, fA, gA, oA, iB, fB, gB, oB;
      QUAD_TRANSPOSE(l, a0, a1, a2, a3, iA, fA, gA, oA);
      QUAD_TRANSPOSE(l, e0, e1v, e2v, e3, iB, fB, gB, oB);
      cA = sigf(fA) * cA + sigf(iA) * tanhf(gA);
      float hA = sigf(oA) * tanhf(cA);
      cB = sigf(fB) * cB + sigf(iB) * tanhf(gB);
      float hB = sigf(oB) * tanhf(cB);
      // pair units (u', u'+1) into one u32 store (partner = lane ^ 4)
      float hA2 = __shfl_xor(hA, 4);
      float hB2 = __shfl_xor(hB, 4);
      if ((l & 4) == 0) {
        const int bA = q * 4 + (nidx & 3);
        const int colp = dcol + u0 + 4 * w + (nidx >> 2);
        union { u32 u; __bf16 h2[2]; } pk;
        pk.h2[0] = (__bf16)hA; pk.h2[1] = (__bf16)hA2;
        ASTORE((u32*)(A.h0 + ((size_t)tt * BT + bA) * HROW + colp), pk.u);
        pk.h2[0] = (__bf16)hB; pk.h2[1] = (__bf16)hB2;
        ASTORE((u32*)(A.h0 + ((size_t)tt * BT + bA + 16) * HROW + colp), pk.u);
      }
    }

    if (s < TT - 1) rec_barrier(A.flags, (unsigned)(s + 1), d * 50, 50);
  }
}

// ---------------- L1: persistent rec (100 WGs) + xg gemm (156 WGs) ----------
struct L1Args {
  const __bf16 *h0, *zero;
  const float *Whh1f, *Whh1b, *Wih1f, *Wih1b, *b1f, *b1b;
  __bf16 *h1, *xg;
  u32* flags;     // lines 0..99: rec; 100..255: gemm
};

__global__ __launch_bounds__(256, 1) void lstm_l1(L1Args A) {
  extern __shared__ __bf16 u2[];
  const int tid = threadIdx.x, w = tid >> 6, l = tid & 63;
  const int nidx = l & 15, q = l >> 4, bL = l & 31, gl = l >> 5;
  __bf16* wlds = u2 + 100 * 256;

  if (blockIdx.x < 100) {
    // ---------------- recurrence consumer ----------------
    const int wg = blockIdx.x, d = wg / 50, u0 = (wg % 50) * 16;
    const int dcol = d * 832;
    // gate-interleaved row (see l0)
    const int row = (nidx & 3) * 800 + u0 + 4 * w + (nidx >> 2);
    {
      const float* wrf = (d ? A.Whh1b : A.Whh1f) + (size_t)row * 800 + q * 8;
#pragma unroll
      for (int sl = 0; sl < 25; ++sl) {
        f32x4 wa = *(const f32x4*)(wrf + sl * 32);
        f32x4 wb = *(const f32x4*)(wrf + sl * 32 + 4);
        *(bf16x8*)(wlds + ((size_t)(w * 25 + sl) * 64 + l) * 8) = cvt8(wa, wb);
      }
    }
    __syncthreads();
    float cA = 0.f, cB = 0.f;

    for (int k = 0; k < NCH; ++k) {
      wait_lines(A.flags, 100, 156, (unsigned)(k + 1));   // xg chunk k ready
      const __bf16* buf = A.xg + (size_t)(k & 1) * SLOT;
      // preload xg for si=0 (L2-bypass: slots are reused -> cached reads unsafe)
      const u64* xga0 = (const u64*)(buf + ((size_t)(d * CH) * 3200 + row) * 32 + q * 4);
      u64 x0 = ALOAD(xga0);
      u64 x1 = ALOAD(xga0 + 4);
#pragma unroll 1
      for (int si = 0; si < CH; ++si) {
        const int s = k * CH + si;
        const int tt = d ? (TT - 1 - s) : s;
        const __bf16* hprev =
            (s == 0) ? A.zero
                     : (A.h1 + (size_t)(d ? tt + 1 : tt - 1) * (BT * HROW));

        u64 cx0 = x0, cx1 = x1;
        if (si + 1 < CH) {
          const u64* xgn = (const u64*)(buf +
              ((size_t)(d * CH + si + 1) * 3200 + row) * 32 + q * 4);
          x0 = ALOAD(xgn);
          x1 = ALOAD(xgn + 4);
        }

        bf16x8 hreg[13];
        const __bf16* hsrc = hprev + (size_t)bL * HROW + dcol;
#pragma unroll
        for (int i = 0; i < 12; ++i)
          hreg[i] = *(const bf16x8*)(hsrc + (i * 8 + w * 2 + gl) * 8);
        if (w < 2) hreg[12] = *(const bf16x8*)(hsrc + (96 + w * 2 + gl) * 8);

        union { u64 u; __bf16 h[4]; } ux0, ux1;
        ux0.u = cx0; ux1.u = cx1;
        f32x4 acc0 = {(float)ux0.h[0], (float)ux0.h[1],
                      (float)ux0.h[2], (float)ux0.h[3]};
        f32x4 acc1 = {(float)ux1.h[0], (float)ux1.h[1],
                      (float)ux1.h[2], (float)ux1.h[3]};

#pragma unroll
        for (int i = 0; i < 12; ++i)
          *(bf16x8*)(u2 + (size_t)(i * 8 + w * 2 + gl) * 256 + bL * 8) = hreg[i];
        if (w < 2)
          *(bf16x8*)(u2 + (size_t)(96 + w * 2 + gl) * 256 + bL * 8) = hreg[12];
        lds_barrier();   // LDS-only: keeps xg prefetch in flight

#pragma unroll
        for (int sl = 0; sl < 25; ++sl) {
          bf16x8 bfr = *(const bf16x8*)(wlds + ((size_t)(w * 25 + sl) * 64 + l) * 8);
          const __bf16* ab = u2 + (size_t)(sl * 4 + q) * 256 + nidx * 8;
          bf16x8 a0 = *(const bf16x8*)ab;
          bf16x8 a1 = *(const bf16x8*)(ab + 128);
          acc0 = mfma16(a0, bfr, acc0);
          acc1 = mfma16(a1, bfr, acc1);
        }

        // in-register gate gather (bias already inside xg)
        {
          float a0 = acc0[0], a1 = acc0[1], a2 = acc0[2], a3 = acc0[3];
          float e0 = acc1[0], e1v = acc1[1], e2v = acc1[2], e3 = acc1[3];
          float iA, fA, gA, oA, iB, fB, gB, oB;
          QUAD_TRANSPOSE(l, a0, a1, a2, a3, iA, fA, gA, oA);
          QUAD_TRANSPOSE(l, e0, e1v, e2v, e3, iB, fB, gB, oB);
          cA = sigf(fA) * cA + sigf(iA) * tanhf(gA);
          float hA = sigf(oA) * tanhf(cA);
          cB = sigf(fB) * cB + sigf(iB) * tanhf(gB);
          float hB = sigf(oB) * tanhf(cB);
          float hA2 = __shfl_xor(hA, 4);
          float hB2 = __shfl_xor(hB, 4);
          if ((l & 4) == 0) {
            const int bA = q * 4 + (nidx & 3);
            const int colp = dcol + u0 + 4 * w + (nidx >> 2);
            union { u32 u; __bf16 h2[2]; } pk;
            pk.h2[0] = (__bf16)hA; pk.h2[1] = (__bf16)hA2;
            ASTORE((u32*)(A.h1 + ((size_t)tt * BT + bA) * HROW + colp), pk.u);
            pk.h2[0] = (__bf16)hB; pk.h2[1] = (__bf16)hB2;
            ASTORE((u32*)(A.h1 + ((size_t)tt * BT + bA + 16) * HROW + colp), pk.u);
          }
        }

        if (s < TT - 1) rec_barrier(A.flags, (unsigned)(s + 1), 0 + d * 50, 50);
      }
    }
  } else {
    // ---------------- xg producer: 156 WGs, 400 half-tile units/chunk ------
    // R4 form (best measured): register prefetch of next slot's h0 rows,
    // issued after barrier A, pinned by sched_barrier(0); lgkm-only barriers.
    const int g = blockIdx.x - 100;
    const int u_begin = (g * 400) / 156;
    const int u_end   = ((g + 1) * 400) / 156;
    const int nslots  = (u_end - u_begin) * 50;
    const int rh = w >> 1, bh = w & 1;

    bf16x8 pre[13];
    f32x4 acc = {0.f, 0.f, 0.f, 0.f};
    int cur_tl = -1;
    float bn = 0.f;
    int rr = 0;

    for (int k = 0; k < NCH; ++k) {
      // slot (k&1) reused by chunk k-2's reader: wait until rec done chunk k-2
      if (k >= 2) wait_lines(A.flags, 0, 100, (unsigned)((k - 1) * CH));
      __bf16* buf = A.xg + (size_t)(k & 1) * SLOT;

      // cold-load slot 0 of this chunk (u_begin, first tloc, pass 0)
      {
        const int th0 = u_begin & 1;
        const int dir0 = (u_begin >> 1) / 100;
        const int tloc0 = th0 * 25;
        const int t0 = dir0 ? (TT - 1 - k * CH - tloc0) : (k * CH + tloc0);
        const __bf16* hs = A.h0 + ((size_t)t0 * BT + bL) * HROW;
#pragma unroll
        for (int i = 0; i < 12; ++i)
          pre[i] = *(const bf16x8*)(hs + (i * 8 + w * 2 + gl) * 8);
        if (w < 2) pre[12] = *(const bf16x8*)(hs + (96 + w * 2 + gl) * 8);
      }

#pragma unroll 1
      for (int s = 0; s < nslots; ++s) {
        const int u = u_begin + s / 50;
        const int r = s % 50;
        const int tl = u >> 1, th = u & 1;
        const int tloc = th * 25 + (r >> 1);
        const int pass = r & 1;
        const int dir = tl / 100, rt = tl % 100;
        const int rbase = rt * 32;

        if (tl != cur_tl) {               // new W tile (only hit at pass==0)
          cur_tl = tl;
          const float* W = dir ? A.Wih1b : A.Wih1f;
          __syncthreads();   // protect wlds from previous tile's MFMAs
          for (int i = w * 25; i < w * 25 + 25; ++i) {
            const int rhh = i / 50, sl = i % 50;
            const int rrr = rbase + rhh * 16 + nidx;
            const float* wp = W + (size_t)rrr * 1600 + sl * 32 + q * 8;
            f32x4 wa = *(const f32x4*)wp;
            f32x4 wb = *(const f32x4*)(wp + 4);
            *(bf16x8*)(wlds + ((size_t)i * 64 + l) * 8) = cvt8(wa, wb);
          }
          __syncthreads();
          rr = rbase + rh * 16 + nidx;
          bn = (dir ? A.b1b : A.b1f)[rr];
        }

        // stage current slot's h0 rows (in pre) into u2
#pragma unroll
        for (int i = 0; i < 12; ++i)
          *(bf16x8*)(u2 + (size_t)(i * 8 + w * 2 + gl) * 256 + bL * 8) = pre[i];
        if (w < 2)
          *(bf16x8*)(u2 + (size_t)(96 + w * 2 + gl) * 256 + bL * 8) = pre[12];
        lds_barrier();   // A: staging visible; no vmcnt drain

        // issue NEXT slot's loads; latency hides under the MFMA chain below
        if (s + 1 < nslots) {
          const int s2 = s + 1;
          const int un = u_begin + s2 / 50;
          const int r2 = s2 % 50;
          const int thn = un & 1;
          const int tlocn = thn * 25 + (r2 >> 1);
          const int passn = r2 & 1;
          const int dirn = (un >> 1) / 100;
          const int tn = dirn ? (TT - 1 - k * CH - tlocn) : (k * CH + tlocn);
          const __bf16* hs = A.h0 + ((size_t)tn * BT + bL) * HROW + passn * 832;
#pragma unroll
          for (int i = 0; i < 12; ++i)
            pre[i] = *(const bf16x8*)(hs + (i * 8 + w * 2 + gl) * 8);
          if (w < 2) pre[12] = *(const bf16x8*)(hs + (96 + w * 2 + gl) * 8);
        }
        __builtin_amdgcn_sched_barrier(0);   // loads may not sink below here

        if (pass == 0) acc = f32x4{0.f, 0.f, 0.f, 0.f};
#pragma unroll
        for (int sl = 0; sl < 25; ++sl) {
          bf16x8 b = *(const bf16x8*)(wlds +
              ((size_t)(rh * 50 + pass * 25 + sl) * 64 + l) * 8);
          bf16x8 a = *(const bf16x8*)(u2 +
              (size_t)(sl * 4 + q) * 256 + (bh * 16 + nidx) * 8);
          acc = mfma16(a, b, acc);
        }
        lds_barrier();   // B: reads done; prefetch stays in flight

        if (pass == 1) {
          union { u64 u; __bf16 h[4]; } pv;
#pragma unroll
          for (int r2 = 0; r2 < 4; ++r2) pv.h[r2] = (__bf16)(acc[r2] + bn);
          ASTORE((u64*)(buf + ((size_t)(dir * CH + tloc) * 3200 + rr) * 32 +
                        bh * 16 + q * 4), pv.u);
        }
      }
      asm volatile("s_waitcnt vmcnt(0)" ::: "memory");   // xg at coherence pt
      __syncthreads();
      if (tid == 0) ASTORE(A.flags + (size_t)(100 + g) * 32, (unsigned)(k + 1));
    }
  }
}

// ---------------- FC + softmax + dihedral -> points ----------------
__global__ __launch_bounds__(256) void fc_kernel(
    const __bf16* __restrict__ h1, const __bf16* __restrict__ xpad,
    const __bf16* __restrict__ wfc, const float* __restrict__ fcb,
    const float* __restrict__ sinA, const float* __restrict__ cosA,
    float* __restrict__ pts) {
  __shared__ float lg[32 * 64];
  const int t = blockIdx.x, tid = threadIdx.x;
  const int wave = tid >> 6, lane = tid & 63, nidx = lane & 15, q = lane >> 4;
  const int a_col = wave * 16 + nidx;
  const __bf16* wrow = wfc + (size_t)a_col * 1664 + q * 8;
  const __bf16* h1row = h1 + (size_t)t * BT * HROW;
  const __bf16* xrow  = xpad + (size_t)t * BT * 64;
  f32x4 acc0 = {0.f, 0.f, 0.f, 0.f}, acc1 = {0.f, 0.f, 0.f, 0.f};
#pragma unroll
  for (int sl = 0; sl < 52; ++sl) {
    const int k = sl * 32 + q * 8;
    bf16x8 a0, a1;
    if (sl < 50) {
      const int kp = (sl < 25) ? k : (k + 32);
      a0 = *(const bf16x8*)(h1row + (size_t)nidx * HROW + kp);
      a1 = *(const bf16x8*)(h1row + (size_t)(16 + nidx) * HROW + kp);
    } else {
      a0 = *(const bf16x8*)(xrow + nidx * 64 + (k - 1600));
      a1 = *(const bf16x8*)(xrow + (16 + nidx) * 64 + (k - 1600));
    }
    bf16x8 bfr = *(const bf16x8*)(wrow + sl * 32);
    acc0 = mfma16(a0, bfr, acc0);
    acc1 = mfma16(a1, bfr, acc1);
  }
  const float bn = (a_col < 60) ? fcb[a_col] : -1e30f;
#pragma unroll
  for (int r = 0; r < 4; ++r) {
    lg[(q * 4 + r) * 64 + a_col]      = acc0[r] + bn;
    lg[(16 + q * 4 + r) * 64 + a_col] = acc1[r] + bn;
  }
  __syncthreads();

  const int b = tid >> 3, j = tid & 7;
  float v[8];
  float m = -1e30f;
#pragma unroll
  for (int k2 = 0; k2 < 8; ++k2) {
    v[k2] = lg[b * 64 + j + 8 * k2];
    m = fmaxf(m, v[k2]);
  }
  m = fmaxf(m, __shfl_xor(m, 1, 8));
  m = fmaxf(m, __shfl_xor(m, 2, 8));
  m = fmaxf(m, __shfl_xor(m, 4, 8));
  float s = 0.f;
#pragma unroll
  for (int k2 = 0; k2 < 8; ++k2) { v[k2] = __expf(v[k2] - m); s += v[k2]; }
  s += __shfl_xor(s, 1, 8);
  s += __shfl_xor(s, 2, 8);
  s += __shfl_xor(s, 4, 8);
  const float inv = 1.f / s;
  float ps[3] = {0.f, 0.f, 0.f}, pc[3] = {0.f, 0.f, 0.f};
#pragma unroll
  for (int k2 = 0; k2 < 8; ++k2) {
    const int a = j + 8 * k2;
    const float p = v[k2] * inv;
#pragma unroll
    for (int c = 0; c < 3; ++c) {
      ps[c] += p * sinA[a * 3 + c];
      pc[c] += p * cosA[a * 3 + c];
    }
  }
#pragma unroll
  for (int c = 0; c < 3; ++c) {
    ps[c] += __shfl_xor(ps[c], 1, 8);
    ps[c] += __shfl_xor(ps[c], 2, 8);
    ps[c] += __shfl_xor(ps[c], 4, 8);
    pc[c] += __shfl_xor(pc[c], 1, 8);
    pc[c] += __shfl_xor(pc[c], 2, 8);
    pc[c] += __shfl_xor(pc[c], 4, 8);
  }
  if (j == 0) {
    const float BL[3] = {145.801f, 152.326f, 132.868f};
    const float BA[3] = {2.124f, 1.941f, 2.028f};
#pragma unroll
    for (int c = 0; c < 3; ++c) {
      const float ang = 3.14159265358979323846f - BA[c];
      const float rct = BL[c] * cosf(ang), rst = BL[c] * sinf(ang);
      const float dih = atan2f(ps[c], pc[c]);
      float* o = pts + ((size_t)(3 * t + c) * BT + b) * 3;
      o[0] = rct;
      o[1] = cosf(dih) * rst;
      o[2] = sinf(dih) * rst;
    }
  }
}

// ---------------- sequential NeRF extension ----------------
__global__ void nerf_kernel(const float* __restrict__ pts, float* __restrict__ out) {
  const int b = threadIdx.x;
  if (b >= 32) return;
  float ax = -0.70710678f, ay = 1.22474487f, az = 0.f;
  float bx = -1.41421356f, by = 0.f, bz = 0.f;
  float cx = 0.f, cy = 0.f, cz = 0.f;
#pragma unroll 4
  for (int i = 0; i < 3 * TT; ++i) {
    const float* p = pts + ((size_t)i * BT + b) * 3;
    const float p0 = p[0], p1 = p[1], p2 = p[2];
    float ux = cx - bx, uy = cy - by, uz = cz - bz;
    const float ri = rsqrtf(ux * ux + uy * uy + uz * uz + 1e-12f);
    ux *= ri; uy *= ri; uz *= ri;
    const float wx = bx - ax, wy = by - ay, wz = bz - az;
    float nx = wy * uz - wz * uy, ny = wz * ux - wx * uz, nz = wx * uy - wy * ux;
    const float rn = rsqrtf(nx * nx + ny * ny + nz * nz + 1e-12f);
    nx *= rn; ny *= rn; nz *= rn;
    const float mx = ny * uz - nz * uy, my = nz * ux - nx * uz, mz = nx * uy - ny * ux;
    const float ox = cx + p0 * ux + p1 * mx + p2 * nx;
    const float oy = cy + p0 * uy + p1 * my + p2 * ny;
    const float oz = cz + p0 * uz + p1 * mz + p2 * nz;
    out[((size_t)i * BT + b) * 3 + 0] = ox;
    out[((size_t)i * BT + b) * 3 + 1] = oy;
    out[((size_t)i * BT + b) * 3 + 2] = oz;
    ax = bx; ay = by; az = bz;
    bx = cx; by = cy; bz = cz;
    cx = ox; cy = oy; cz = oz;
  }
}

// ---------------- launch ----------------
extern "C" void kernel_launch(void* const* d_in, const int* in_sizes, int n_in,
                              void* d_out, int out_size, void* d_ws, size_t ws_size,
                              hipStream_t stream) {
  (void)in_sizes; (void)n_in; (void)out_size;
  const int*   primary = (const int*)d_in[0];
  const float* evo     = (const float*)d_in[1];
  const float* emb     = (const float*)d_in[3];
  const float* Wih0f   = (const float*)d_in[4];
  const float* Whh0f   = (const float*)d_in[5];
  const float* b0f     = (const float*)d_in[6];
  const float* Wih0b   = (const float*)d_in[7];
  const float* Whh0b   = (const float*)d_in[8];
  const float* b0b     = (const float*)d_in[9];
  const float* Wih1f   = (const float*)d_in[10];
  const float* Whh1f   = (const float*)d_in[11];
  const float* b1f     = (const float*)d_in[12];
  const float* Wih1b   = (const float*)d_in[13];
  const float* Whh1b   = (const float*)d_in[14];
  const float* b1b     = (const float*)d_in[15];
  const float* fcW     = (const float*)d_in[16];
  const float* fcb     = (const float*)d_in[17];
  const float* alpha   = (const float*)d_in[18];

  char* ws = (char*)d_ws;
  size_t off = 0;
  auto take = [&](size_t n) -> void* {
    void* p = ws + off;
    off += (n + 511) & ~(size_t)511;
    return p;
  };
  __bf16* xpad = (__bf16*)take((size_t)TT * BT * 64 * 2);
  __bf16* zb   = (__bf16*)take((size_t)BT * HROW * 2);
  __bf16* wx0  = (__bf16*)take((size_t)2 * 3200 * 64 * 2);
  __bf16* wfc  = (__bf16*)take((size_t)64 * 1664 * 2);
  float*  sinA = (float*)take(192 * 4);
  float*  cosA = (float*)take(192 * 4);
  float*  pts  = (float*)take((size_t)3 * TT * BT * 3 * 4);
  u32*    flags0 = (u32*)take(11392 * 4);      // l0: 100 lines; l1: 256 lines
  u32*    flags1 = flags0 + 3200;
  __bf16* xg   = (__bf16*)take(2 * SLOT * 2);  // 41 MB, 2-slot ring
  __bf16* h0   = (__bf16*)take((size_t)TT * BT * HROW * 2);
  __bf16* h1   = (__bf16*)take((size_t)TT * BT * HROW * 2);
  if (off > ws_size) return;  // failure signature: absmax == max|ref| == 233472

  static int lds_cfg = 0;
  if (!lds_cfg) {
    hipFuncSetAttribute((const void*)lstm_l0,
                        hipFuncAttributeMaxDynamicSharedMemorySize, LDS_L0);
    hipFuncSetAttribute((const void*)lstm_l1,
                        hipFuncAttributeMaxDynamicSharedMemorySize, LDS_L1);
    lds_cfg = 1;
  }

  pack_wx0_kernel<<<1600, 256, 0, stream>>>(Wih0f, Wih0b, wx0);
  pack_fc_kernel<<<(64 * 1664 + 255) / 256, 256, 0, stream>>>(fcW, wfc);
  xpad_kernel<<<(TT * BT * 64) / 256, 256, 0, stream>>>(primary, evo, emb, xpad);
  small_init_kernel<<<209, 256, 0, stream>>>(zb, flags0, sinA, cosA, alpha);

  L0Args a0;
  a0.xpad = xpad; a0.wx0 = wx0; a0.zero = zb;
  a0.Whh0f = Whh0f; a0.Whh0b = Whh0b; a0.b0f = b0f; a0.b0b = b0b;
  a0.h0 = h0; a0.flags = flags0;
  lstm_l0<<<100, 256, LDS_L0, stream>>>(a0);

  L1Args a1;
  a1.h0 = h0; a1.zero = zb;
  a1.Whh1f = Whh1f; a1.Whh1b = Whh1b;
  a1.Wih1f = Wih1f; a1.Wih1b = Wih1b;
  a1.b1f = b1f; a1.b1b = b1b;
  a1.h1 = h1; a1.xg = xg; a1.flags = flags1;
  lstm_l1<<<256, 256, LDS_L1, stream>>>(a1);

  fc_kernel<<<TT, 256, 0, stream>>>(h1, xpad, wfc, fcb, sinA, cosA, pts);
  nerf_kernel<<<1, 64, 0, stream>>>(pts, (float*)d_out);
}

// Round 8
// 9061.955 us; speedup vs baseline: 1.0243x; 1.0152x over previous
//
#include <hip/hip_runtime.h>
#include <hip/hip_bf16.h>
#include <math.h>

// ---------------------------------------------------------------------------
// RGN model: T=700 B=32 H=800 EMB=32 EVO=21 A=60
// f32 in / f32 out; internal bf16 MFMA.
// R8: fused l0+l1 persistent kernel (256 WGs), R7 race FIXED:
//   h0[t] is complete only at l0 gen >= max(t+1, 700-t) (fwd half written at
//   s=t, bwd half at s=699-t). Chunk gate = max((k+1)*50, 700-k*50).
//   Availability is middle-out -> production order P = [6,7,5,8,0,1,2,3,4,
//   9..13]: pre-produce 4 middle chunks during l0's tail, then rec-priority.
//   xg buffer = 6 slots with static collision-free slot map + per-position
//   reuse-waits (deadlock-checked). Fallback (ws too small): 2 slots,
//   identity order (serial, R6-equivalent).
// Rec/gemm inner bodies identical to R6 (bit-identical numerics).
// ---------------------------------------------------------------------------

typedef unsigned int u32;
typedef unsigned long long u64;
typedef __bf16 bf16x8 __attribute__((ext_vector_type(8)));
typedef float  f32x4  __attribute__((ext_vector_type(4)));

#define TT 700
#define BT 32
#define HROW 1664          // 800 fwd | 32 pad | 800 bwd | 32 pad
#define CH 50              // chunk length (14 chunks)
#define NCH (TT / CH)
#define SLOT ((size_t)2 * CH * 3200 * 32)      // bf16 elems per xg slot
#define LDS_FU (108 * 512 + 102400)   // 157,696 B (l0 layout, used by all)

__device__ __forceinline__ f32x4 mfma16(bf16x8 a, bf16x8 b, f32x4 c) {
  return __builtin_amdgcn_mfma_f32_16x16x32_bf16(a, b, c, 0, 0, 0);
}
__device__ __forceinline__ float sigf(float x) { return 1.f / (1.f + __expf(-x)); }

#define ALOAD(p)    __hip_atomic_load((p), __ATOMIC_RELAXED, __HIP_MEMORY_SCOPE_AGENT)
#define ASTORE(p,v) __hip_atomic_store((p), (v), __ATOMIC_RELAXED, __HIP_MEMORY_SCOPE_AGENT)

// LDS-only workgroup barrier: does NOT drain vmcnt.
__device__ __forceinline__ void lds_barrier() {
  asm volatile("s_waitcnt lgkmcnt(0)" ::: "memory");
  __builtin_amdgcn_s_barrier();
}

__device__ __forceinline__ bf16x8 cvt8(f32x4 a, f32x4 b) {
  bf16x8 r;
  r[0] = (__bf16)a[0]; r[1] = (__bf16)a[1]; r[2] = (__bf16)a[2]; r[3] = (__bf16)a[3];
  r[4] = (__bf16)b[0]; r[5] = (__bf16)b[1]; r[6] = (__bf16)b[2]; r[7] = (__bf16)b[3];
  return r;
}

// 4x4 transpose across lane quads (see R6).
#define QUAD_TRANSPOSE(l_, a0, a1, a2, a3, o0, o1, o2, o3)                   \
  {                                                                          \
    float s0 = __shfl_xor(a0, 1), s1 = __shfl_xor(a1, 1);                    \
    float s2 = __shfl_xor(a2, 1), s3 = __shfl_xor(a3, 1);                    \
    const bool e1 = ((l_) & 1) == 0;                                         \
    float n0 = e1 ? a0 : s1, n1 = e1 ? s0 : a1;                              \
    float n2 = e1 ? a2 : s3, n3 = e1 ? s2 : a3;                              \
    float t0 = __shfl_xor(n0, 2), t1 = __shfl_xor(n1, 2);                    \
    float t2 = __shfl_xor(n2, 2), t3 = __shfl_xor(n3, 2);                    \
    const bool e2 = ((l_) & 2) == 0;                                         \
    o0 = e2 ? n0 : t2; o1 = e2 ? n1 : t3;                                    \
    o2 = e2 ? t0 : n2; o3 = e2 ? t1 : n3;                                    \
  }

// ---------------- pack / init kernels ----------------
__global__ void pack_wx0_kernel(const float* Wih0f, const float* Wih0b, __bf16* wx0) {
  int idx = blockIdx.x * 256 + threadIdx.x;      // 2*3200*64 exact
  if (idx >= 2 * 3200 * 64) return;
  int d = idx / (3200 * 64);
  int r = (idx / 64) % 3200;
  int k = idx % 64;
  const float* W = d ? Wih0b : Wih0f;
  wx0[idx] = (k < 53) ? (__bf16)W[(size_t)r * 53 + k] : (__bf16)0.f;
}

__global__ void pack_fc_kernel(const float* fcW, __bf16* wfc) {
  int idx = blockIdx.x * 256 + threadIdx.x;
  if (idx >= 64 * 1664) return;
  int a = idx / 1664, k = idx % 1664;
  __bf16 v = (__bf16)0.f;
  if (a < 60 && k < 1653) v = (__bf16)fcW[(size_t)a * 1653 + k];
  wfc[idx] = v;
}

__global__ void xpad_kernel(const int* primary, const float* evo,
                            const float* emb, __bf16* xpad) {
  int idx = blockIdx.x * 256 + threadIdx.x;   // 700*32*64 exact
  int t = idx >> 11;
  int b = (idx >> 6) & 31;
  int k = idx & 63;
  __bf16 v = (__bf16)0.f;
  if (k < 32)      v = (__bf16)emb[primary[t * 32 + b] * 32 + k];
  else if (k < 53) v = (__bf16)evo[((size_t)t * 32 + b) * 21 + (k - 32)];
  xpad[idx] = v;
}

__global__ void small_init_kernel(__bf16* zerobuf, u32* flags,
                                  float* sinA, float* cosA, const float* alpha) {
  int idx = blockIdx.x * 256 + threadIdx.x;
  if (idx < 32 * HROW) zerobuf[idx] = (__bf16)0.f;
  if (idx < 11392) flags[idx] = 0u;   // f0: 100 lines; f1: 256 lines (x32 u32)
  int j = idx - 32 * HROW;
  if (j >= 0 && j < 192) {
    if (j < 180) {
      float v = alpha[j];
      sinA[j] = sinf(v);
      cosA[j] = cosf(v);
    } else { sinA[j] = 0.f; cosA[j] = 0.f; }
  }
}

// ---------------- flag helpers ----------------
__device__ __forceinline__ void wait_lines(u32* flags, int base, int count,
                                           unsigned gen) {
  const int tid = threadIdx.x;
  if (tid < 64) {
    int spin = 0;
    for (;;) {
      bool ok = true;
      for (int j = tid; j < count; j += 64)
        ok = ok && (ALOAD(flags + (size_t)(base + j) * 32) >= gen);
      if (__popcll(__ballot(ok)) == 64) break;
      if (++spin > 24) __builtin_amdgcn_s_sleep(1);
    }
  }
  __syncthreads();
}

__device__ __forceinline__ void rec_barrier(u32* flags, unsigned gen,
                                            int base, int count) {
  asm volatile("s_waitcnt vmcnt(0)" ::: "memory");
  __syncthreads();
  if (threadIdx.x == 0) ASTORE(flags + (size_t)blockIdx.x * 32, gen);
  wait_lines(flags, base, count, gen);
}

// ---------------- fused L0+L1 persistent kernel ----------------
struct FusedArgs {
  const __bf16 *xpad, *wx0, *zero;
  const float *Whh0f, *Whh0b, *b0f, *b0b;
  const float *Whh1f, *Whh1b, *Wih1f, *Wih1b, *b1f, *b1b;
  __bf16 *h0, *h1, *xg;
  u32 *f0, *f1;   // f0: l0 rec lines 0..99; f1: lines 0..99 rec, 100..255 gemm
  int mode;       // 1 = 6-slot middle-out overlap; 0 = 2-slot serial fallback
};

__global__ __launch_bounds__(256, 1) void lstm_fused(FusedArgs A) {
  extern __shared__ __bf16 u2[];
  const int tid = threadIdx.x, w = tid >> 6, l = tid & 63;
  const int nidx = l & 15, q = l >> 4, bL = l & 31, gl = l >> 5;
  __bf16* wlds = u2 + 108 * 256;

  if (blockIdx.x < 100) {
    const int wg = blockIdx.x, d = wg / 50, u0 = (wg % 50) * 16;
    const int dcol = d * 832;
    // gate-interleaved row: N-slot nidx -> gate nidx&3, unit u0+4w+(nidx>>2)
    const int row = (nidx & 3) * 800 + u0 + 4 * w + (nidx >> 2);

    // ================= phase 1: L0 recurrence =================
    {
      const float bias_n = (d ? A.b0b : A.b0f)[row];
      const float* wrf = (d ? A.Whh0b : A.Whh0f) + (size_t)row * 800 + q * 8;
#pragma unroll
      for (int sl = 0; sl < 25; ++sl) {
        f32x4 wa = *(const f32x4*)(wrf + sl * 32);
        f32x4 wb = *(const f32x4*)(wrf + sl * 32 + 4);
        *(bf16x8*)(wlds + ((size_t)(w * 25 + sl) * 64 + l) * 8) = cvt8(wa, wb);
      }
      const __bf16* wx_row = A.wx0 + (size_t)d * 3200 * 64 + (size_t)row * 64 + q * 8;
      bf16x8 wx_r0 = *(const bf16x8*)wx_row;
      bf16x8 wx_r1 = *(const bf16x8*)(wx_row + 32);
      __syncthreads();

      float cA = 0.f, cB = 0.f;
#pragma unroll 1
      for (int s = 0; s < TT; ++s) {
        const int tt = d ? (TT - 1 - s) : s;
        const __bf16* hprev =
            (s == 0) ? A.zero : (A.h0 + (size_t)(d ? tt + 1 : tt - 1) * (BT * HROW));

        bf16x8 hreg[13];
        const __bf16* hsrc = hprev + (size_t)bL * HROW + dcol;
#pragma unroll
        for (int i = 0; i < 12; ++i)
          hreg[i] = *(const bf16x8*)(hsrc + (i * 8 + w * 2 + gl) * 8);
        if (w < 2) hreg[12] = *(const bf16x8*)(hsrc + (96 + w * 2 + gl) * 8);
        bf16x8 xv = *(const bf16x8*)(A.xpad + ((size_t)tt * BT + bL) * 64 + (tid >> 5) * 8);

#pragma unroll
        for (int i = 0; i < 12; ++i)
          *(bf16x8*)(u2 + (size_t)(i * 8 + w * 2 + gl) * 256 + bL * 8) = hreg[i];
        if (w < 2)
          *(bf16x8*)(u2 + (size_t)(96 + w * 2 + gl) * 256 + bL * 8) = hreg[12];
        *(bf16x8*)(u2 + (size_t)(100 + (tid >> 5)) * 256 + bL * 8) = xv;
        __syncthreads();

        f32x4 acc0 = {0.f, 0.f, 0.f, 0.f}, acc1 = {0.f, 0.f, 0.f, 0.f};
#pragma unroll
        for (int sl = 0; sl < 27; ++sl) {
          bf16x8 bfr;
          if (sl < 25)
            bfr = *(const bf16x8*)(wlds + ((size_t)(w * 25 + sl) * 64 + l) * 8);
          else
            bfr = (sl == 25) ? wx_r0 : wx_r1;
          const __bf16* ab = u2 + (size_t)(sl * 4 + q) * 256 + nidx * 8;
          bf16x8 a0 = *(const bf16x8*)ab;
          bf16x8 a1 = *(const bf16x8*)(ab + 128);
          acc0 = mfma16(a0, bfr, acc0);
          acc1 = mfma16(a1, bfr, acc1);
        }

        {
          float a0 = acc0[0] + bias_n, a1 = acc0[1] + bias_n,
                a2 = acc0[2] + bias_n, a3 = acc0[3] + bias_n;
          float e0 = acc1[0] + bias_n, e1v = acc1[1] + bias_n,
                e2v = acc1[2] + bias_n, e3 = acc1[3] + bias_n;
          float iA, fA, gA, oA, iB, fB, gB, oB;
          QUAD_TRANSPOSE(l, a0, a1, a2, a3, iA, fA, gA, oA);
          QUAD_TRANSPOSE(l, e0, e1v, e2v, e3, iB, fB, gB, oB);
          cA = sigf(fA) * cA + sigf(iA) * tanhf(gA);
          float hA = sigf(oA) * tanhf(cA);
          cB = sigf(fB) * cB + sigf(iB) * tanhf(gB);
          float hB = sigf(oB) * tanhf(cB);
          float hA2 = __shfl_xor(hA, 4);
          float hB2 = __shfl_xor(hB, 4);
          if ((l & 4) == 0) {
            const int bA = q * 4 + (nidx & 3);
            const int colp = dcol + u0 + 4 * w + (nidx >> 2);
            union { u32 u; __bf16 h2[2]; } pk;
            pk.h2[0] = (__bf16)hA; pk.h2[1] = (__bf16)hA2;
            ASTORE((u32*)(A.h0 + ((size_t)tt * BT + bA) * HROW + colp), pk.u);
            pk.h2[0] = (__bf16)hB; pk.h2[1] = (__bf16)hB2;
            ASTORE((u32*)(A.h0 + ((size_t)tt * BT + bA + 16) * HROW + colp), pk.u);
          }
        }

        if (s < TT - 1) rec_barrier(A.f0, (unsigned)(s + 1), d * 50, 50);
      }

      // final flag: h0 complete & visible (gen TT = 700)
      asm volatile("s_waitcnt vmcnt(0)" ::: "memory");
      __syncthreads();
      if (tid == 0) ASTORE(A.f0 + (size_t)wg * 32, (unsigned)TT);
    }

    // ================= phase 2: L1 recurrence =================
    {
      const int POS1[14]  = {4, 5, 6, 7, 8, 2, 0, 1, 3, 9, 10, 11, 12, 13};
      const int SLOT1[14] = {4, 5, 4, 5, 4, 2, 0, 1, 3, 5, 0, 1, 2, 3};
      const float* wrf = (d ? A.Whh1b : A.Whh1f) + (size_t)row * 800 + q * 8;
      __syncthreads();
#pragma unroll
      for (int sl = 0; sl < 25; ++sl) {
        f32x4 wa = *(const f32x4*)(wrf + sl * 32);
        f32x4 wb = *(const f32x4*)(wrf + sl * 32 + 4);
        *(bf16x8*)(wlds + ((size_t)(w * 25 + sl) * 64 + l) * 8) = cvt8(wa, wb);
      }
      __syncthreads();
      float cA = 0.f, cB = 0.f;

      for (int k = 0; k < NCH; ++k) {
        // xg chunk k ready once all 156 gemm WGs produced its position
        const int pos = A.mode ? POS1[k] : k;
        wait_lines(A.f1, 100, 156, (unsigned)(pos + 1));
        const int slot = A.mode ? SLOT1[k] : (k & 1);
        const __bf16* buf = A.xg + (size_t)slot * SLOT;
        const u64* xga0 = (const u64*)(buf + ((size_t)(d * CH) * 3200 + row) * 32 + q * 4);
        u64 x0 = ALOAD(xga0);
        u64 x1 = ALOAD(xga0 + 4);
#pragma unroll 1
        for (int si = 0; si < CH; ++si) {
          const int s = k * CH + si;
          const int tt = d ? (TT - 1 - s) : s;
          const __bf16* hprev =
              (s == 0) ? A.zero
                       : (A.h1 + (size_t)(d ? tt + 1 : tt - 1) * (BT * HROW));

          u64 cx0 = x0, cx1 = x1;
          if (si + 1 < CH) {
            const u64* xgn = (const u64*)(buf +
                ((size_t)(d * CH + si + 1) * 3200 + row) * 32 + q * 4);
            x0 = ALOAD(xgn);
            x1 = ALOAD(xgn + 4);
          }

          bf16x8 hreg[13];
          const __bf16* hsrc = hprev + (size_t)bL * HROW + dcol;
#pragma unroll
          for (int i = 0; i < 12; ++i)
            hreg[i] = *(const bf16x8*)(hsrc + (i * 8 + w * 2 + gl) * 8);
          if (w < 2) hreg[12] = *(const bf16x8*)(hsrc + (96 + w * 2 + gl) * 8);

          union { u64 u; __bf16 h[4]; } ux0, ux1;
          ux0.u = cx0; ux1.u = cx1;
          f32x4 acc0 = {(float)ux0.h[0], (float)ux0.h[1],
                        (float)ux0.h[2], (float)ux0.h[3]};
          f32x4 acc1 = {(float)ux1.h[0], (float)ux1.h[1],
                        (float)ux1.h[2], (float)ux1.h[3]};

#pragma unroll
          for (int i = 0; i < 12; ++i)
            *(bf16x8*)(u2 + (size_t)(i * 8 + w * 2 + gl) * 256 + bL * 8) = hreg[i];
          if (w < 2)
            *(bf16x8*)(u2 + (size_t)(96 + w * 2 + gl) * 256 + bL * 8) = hreg[12];
          lds_barrier();   // LDS-only: keeps xg prefetch in flight

#pragma unroll
          for (int sl = 0; sl < 25; ++sl) {
            bf16x8 bfr = *(const bf16x8*)(wlds + ((size_t)(w * 25 + sl) * 64 + l) * 8);
            const __bf16* ab = u2 + (size_t)(sl * 4 + q) * 256 + nidx * 8;
            bf16x8 a0 = *(const bf16x8*)ab;
            bf16x8 a1 = *(const bf16x8*)(ab + 128);
            acc0 = mfma16(a0, bfr, acc0);
            acc1 = mfma16(a1, bfr, acc1);
          }

          {
            float a0 = acc0[0], a1 = acc0[1], a2 = acc0[2], a3 = acc0[3];
            float e0 = acc1[0], e1v = acc1[1], e2v = acc1[2], e3 = acc1[3];
            float iA, fA, gA, oA, iB, fB, gB, oB;
            QUAD_TRANSPOSE(l, a0, a1, a2, a3, iA, fA, gA, oA);
            QUAD_TRANSPOSE(l, e0, e1v, e2v, e3, iB, fB, gB, oB);
            cA = sigf(fA) * cA + sigf(iA) * tanhf(gA);
            float hA = sigf(oA) * tanhf(cA);
            cB = sigf(fB) * cB + sigf(iB) * tanhf(gB);
            float hB = sigf(oB) * tanhf(cB);
            float hA2 = __shfl_xor(hA, 4);
            float hB2 = __shfl_xor(hB, 4);
            if ((l & 4) == 0) {
              const int bA = q * 4 + (nidx & 3);
              const int colp = dcol + u0 + 4 * w + (nidx >> 2);
              union { u32 u; __bf16 h2[2]; } pk;
              pk.h2[0] = (__bf16)hA; pk.h2[1] = (__bf16)hA2;
              ASTORE((u32*)(A.h1 + ((size_t)tt * BT + bA) * HROW + colp), pk.u);
              pk.h2[0] = (__bf16)hB; pk.h2[1] = (__bf16)hB2;
              ASTORE((u32*)(A.h1 + ((size_t)tt * BT + bA + 16) * HROW + colp), pk.u);
            }
          }

          if (s < TT - 1) rec_barrier(A.f1, (unsigned)(s + 1), 0 + d * 50, 50);
        }
      }
    }
  } else {
    // ============ xg producer: 156 WGs, chases l0 (middle-out) ============
    // mode 1: production order P1, slot map SLOT1, reuse-wait table WAIT1
    //   (by production position; deadlock-checked against consumption order).
    // mode 0: identity order, 2 slots, reuse-wait chunk ki-2 (serial).
    const int P1[14]    = {6, 7, 5, 8, 0, 1, 2, 3, 4, 9, 10, 11, 12, 13};
    const int WAIT1[14] = {-1,-1,-1,-1,-1,-1, 0, 1, 2, 3, 6, 7, 5, 8};
    const int SLOT1[14] = {4, 5, 4, 5, 4, 2, 0, 1, 3, 5, 0, 1, 2, 3};
    const int g = blockIdx.x - 100;
    const int u_begin = (g * 400) / 156;
    const int u_end   = ((g + 1) * 400) / 156;
    const int nslots  = (u_end - u_begin) * 50;
    const int rh = w >> 1, bh = w & 1;

    bf16x8 pre[13];
    f32x4 acc = {0.f, 0.f, 0.f, 0.f};
    int cur_tl = -1;
    float bn = 0.f;
    int rr = 0;

    for (int ki = 0; ki < NCH; ++ki) {
      const int k = A.mode ? P1[ki] : ki;
      // h0 chunk k complete at l0 gen max((k+1)*50, 700-k*50):
      // fwd half of row t written at s=t, bwd half at s=699-t.
      {
        const int n1 = (k + 1) * CH, n2 = TT - k * CH;
        wait_lines(A.f0, 0, 100, (unsigned)(n1 > n2 ? n1 : n2));
      }
      // slot reuse: wait until previous occupant chunk is consumed by rec
      const int wc = A.mode ? WAIT1[ki] : (ki - 2);
      if (wc >= 0) wait_lines(A.f1, 0, 100, (unsigned)((wc + 1) * CH));
      __bf16* buf = A.xg + (size_t)(A.mode ? SLOT1[k] : (k & 1)) * SLOT;

      // cold-load slot 0 of this chunk (u_begin, first tloc, pass 0)
      {
        const int th0 = u_begin & 1;
        const int dir0 = (u_begin >> 1) / 100;
        const int tloc0 = th0 * 25;
        const int t0 = dir0 ? (TT - 1 - k * CH - tloc0) : (k * CH + tloc0);
        const __bf16* hs = A.h0 + ((size_t)t0 * BT + bL) * HROW;
#pragma unroll
        for (int i = 0; i < 12; ++i)
          pre[i] = *(const bf16x8*)(hs + (i * 8 + w * 2 + gl) * 8);
        if (w < 2) pre[12] = *(const bf16x8*)(hs + (96 + w * 2 + gl) * 8);
      }

#pragma unroll 1
      for (int s = 0; s < nslots; ++s) {
        const int u = u_begin + s / 50;
        const int r = s % 50;
        const int tl = u >> 1, th = u & 1;
        const int tloc = th * 25 + (r >> 1);
        const int pass = r & 1;
        const int dir = tl / 100, rt = tl % 100;
        const int rbase = rt * 32;

        if (tl != cur_tl) {               // new W tile (only hit at pass==0)
          cur_tl = tl;
          const float* W = dir ? A.Wih1b : A.Wih1f;
          __syncthreads();   // protect wlds from previous tile's MFMAs
          for (int i = w * 25; i < w * 25 + 25; ++i) {
            const int rhh = i / 50, sl = i % 50;
            const int rrr = rbase + rhh * 16 + nidx;
            const float* wp = W + (size_t)rrr * 1600 + sl * 32 + q * 8;
            f32x4 wa = *(const f32x4*)wp;
            f32x4 wb = *(const f32x4*)(wp + 4);
            *(bf16x8*)(wlds + ((size_t)i * 64 + l) * 8) = cvt8(wa, wb);
          }
          __syncthreads();
          rr = rbase + rh * 16 + nidx;
          bn = (dir ? A.b1b : A.b1f)[rr];
        }

        // stage current slot's h0 rows (in pre) into u2
#pragma unroll
        for (int i = 0; i < 12; ++i)
          *(bf16x8*)(u2 + (size_t)(i * 8 + w * 2 + gl) * 256 + bL * 8) = pre[i];
        if (w < 2)
          *(bf16x8*)(u2 + (size_t)(96 + w * 2 + gl) * 256 + bL * 8) = pre[12];
        lds_barrier();   // A: staging visible; no vmcnt drain

        // issue NEXT slot's loads; latency hides under the MFMA chain below
        if (s + 1 < nslots) {
          const int s2 = s + 1;
          const int un = u_begin + s2 / 50;
          const int r2 = s2 % 50;
          const int thn = un & 1;
          const int tlocn = thn * 25 + (r2 >> 1);
          const int passn = r2 & 1;
          const int dirn = (un >> 1) / 100;
          const int tn = dirn ? (TT - 1 - k * CH - tlocn) : (k * CH + tlocn);
          const __bf16* hs = A.h0 + ((size_t)tn * BT + bL) * HROW + passn * 832;
#pragma unroll
          for (int i = 0; i < 12; ++i)
            pre[i] = *(const bf16x8*)(hs + (i * 8 + w * 2 + gl) * 8);
          if (w < 2) pre[12] = *(const bf16x8*)(hs + (96 + w * 2 + gl) * 8);
        }
        __builtin_amdgcn_sched_barrier(0);   // loads may not sink below here

        if (pass == 0) acc = f32x4{0.f, 0.f, 0.f, 0.f};
#pragma unroll
        for (int sl = 0; sl < 25; ++sl) {
          bf16x8 b = *(const bf16x8*)(wlds +
              ((size_t)(rh * 50 + pass * 25 + sl) * 64 + l) * 8);
          bf16x8 a = *(const bf16x8*)(u2 +
              (size_t)(sl * 4 + q) * 256 + (bh * 16 + nidx) * 8);
          acc = mfma16(a, b, acc);
        }
        lds_barrier();   // B: reads done; prefetch stays in flight

        if (pass == 1) {
          union { u64 u; __bf16 h[4]; } pv;
#pragma unroll
          for (int r2 = 0; r2 < 4; ++r2) pv.h[r2] = (__bf16)(acc[r2] + bn);
          ASTORE((u64*)(buf + ((size_t)(dir * CH + tloc) * 3200 + rr) * 32 +
                        bh * 16 + q * 4), pv.u);
        }
      }
      asm volatile("s_waitcnt vmcnt(0)" ::: "memory");   // xg at coherence pt
      __syncthreads();
      if (tid == 0) ASTORE(A.f1 + (size_t)(100 + g) * 32, (unsigned)(ki + 1));
    }
  }
}

// ---------------- FC + softmax + dihedral -> points ----------------
__global__ __launch_bounds__(256) void fc_kernel(
    const __bf16* __restrict__ h1, const __bf16* __restrict__ xpad,
    const __bf16* __restrict__ wfc, const float* __restrict__ fcb,
    const float* __restrict__ sinA, const float* __restrict__ cosA,
    float* __restrict__ pts) {
  __shared__ float lg[32 * 64];
  const int t = blockIdx.x, tid = threadIdx.x;
  const int wave = tid >> 6, lane = tid & 63, nidx = lane & 15, q = lane >> 4;
  const int a_col = wave * 16 + nidx;
  const __bf16* wrow = wfc + (size_t)a_col * 1664 + q * 8;
  const __bf16* h1row = h1 + (size_t)t * BT * HROW;
  const __bf16* xrow  = xpad + (size_t)t * BT * 64;
  f32x4 acc0 = {0.f, 0.f, 0.f, 0.f}, acc1 = {0.f, 0.f, 0.f, 0.f};
#pragma unroll
  for (int sl = 0; sl < 52; ++sl) {
    const int k = sl * 32 + q * 8;
    bf16x8 a0, a1;
    if (sl < 50) {
      const int kp = (sl < 25) ? k : (k + 32);
      a0 = *(const bf16x8*)(h1row + (size_t)nidx * HROW + kp);
      a1 = *(const bf16x8*)(h1row + (size_t)(16 + nidx) * HROW + kp);
    } else {
      a0 = *(const bf16x8*)(xrow + nidx * 64 + (k - 1600));
      a1 = *(const bf16x8*)(xrow + (16 + nidx) * 64 + (k - 1600));
    }
    bf16x8 bfr = *(const bf16x8*)(wrow + sl * 32);
    acc0 = mfma16(a0, bfr, acc0);
    acc1 = mfma16(a1, bfr, acc1);
  }
  const float bn = (a_col < 60) ? fcb[a_col] : -1e30f;
#pragma unroll
  for (int r = 0; r < 4; ++r) {
    lg[(q * 4 + r) * 64 + a_col]      = acc0[r] + bn;
    lg[(16 + q * 4 + r) * 64 + a_col] = acc1[r] + bn;
  }
  __syncthreads();

  const int b = tid >> 3, j = tid & 7;
  float v[8];
  float m = -1e30f;
#pragma unroll
  for (int k2 = 0; k2 < 8; ++k2) {
    v[k2] = lg[b * 64 + j + 8 * k2];
    m = fmaxf(m, v[k2]);
  }
  m = fmaxf(m, __shfl_xor(m, 1, 8));
  m = fmaxf(m, __shfl_xor(m, 2, 8));
  m = fmaxf(m, __shfl_xor(m, 4, 8));
  float s = 0.f;
#pragma unroll
  for (int k2 = 0; k2 < 8; ++k2) { v[k2] = __expf(v[k2] - m); s += v[k2]; }
  s += __shfl_xor(s, 1, 8);
  s += __shfl_xor(s, 2, 8);
  s += __shfl_xor(s, 4, 8);
  const float inv = 1.f / s;
  float ps[3] = {0.f, 0.f, 0.f}, pc[3] = {0.f, 0.f, 0.f};
#pragma unroll
  for (int k2 = 0; k2 < 8; ++k2) {
    const int a = j + 8 * k2;
    const float p = v[k2] * inv;
#pragma unroll
    for (int c = 0; c < 3; ++c) {
      ps[c] += p * sinA[a * 3 + c];
      pc[c] += p * cosA[a * 3 + c];
    }
  }
#pragma unroll
  for (int c = 0; c < 3; ++c) {
    ps[c] += __shfl_xor(ps[c], 1, 8);
    ps[c] += __shfl_xor(ps[c], 2, 8);
    ps[c] += __shfl_xor(ps[c], 4, 8);
    pc[c] += __shfl_xor(pc[c], 1, 8);
    pc[c] += __shfl_xor(pc[c], 2, 8);
    pc[c] += __shfl_xor(pc[c], 4, 8);
  }
  if (j == 0) {
    const float BL[3] = {145.801f, 152.326f, 132.868f};
    const float BA[3] = {2.124f, 1.941f, 2.028f};
#pragma unroll
    for (int c = 0; c < 3; ++c) {
      const float ang = 3.14159265358979323846f - BA[c];
      const float rct = BL[c] * cosf(ang), rst = BL[c] * sinf(ang);
      const float dih = atan2f(ps[c], pc[c]);
      float* o = pts + ((size_t)(3 * t + c) * BT + b) * 3;
      o[0] = rct;
      o[1] = cosf(dih) * rst;
      o[2] = sinf(dih) * rst;
    }
  }
}

// ---------------- sequential NeRF extension ----------------
__global__ void nerf_kernel(const float* __restrict__ pts, float* __restrict__ out) {
  const int b = threadIdx.x;
  if (b >= 32) return;
  float ax = -0.70710678f, ay = 1.22474487f, az = 0.f;
  float bx = -1.41421356f, by = 0.f, bz = 0.f;
  float cx = 0.f, cy = 0.f, cz = 0.f;
#pragma unroll 4
  for (int i = 0; i < 3 * TT; ++i) {
    const float* p = pts + ((size_t)i * BT + b) * 3;
    const float p0 = p[0], p1 = p[1], p2 = p[2];
    float ux = cx - bx, uy = cy - by, uz = cz - bz;
    const float ri = rsqrtf(ux * ux + uy * uy + uz * uz + 1e-12f);
    ux *= ri; uy *= ri; uz *= ri;
    const float wx = bx - ax, wy = by - ay, wz = bz - az;
    float nx = wy * uz - wz * uy, ny = wz * ux - wx * uz, nz = wx * uy - wy * ux;
    const float rn = rsqrtf(nx * nx + ny * ny + nz * nz + 1e-12f);
    nx *= rn; ny *= rn; nz *= rn;
    const float mx = ny * uz - nz * uy, my = nz * ux - nx * uz, mz = nx * uy - ny * ux;
    const float ox = cx + p0 * ux + p1 * mx + p2 * nx;
    const float oy = cy + p0 * uy + p1 * my + p2 * ny;
    const float oz = cz + p0 * uz + p1 * mz + p2 * nz;
    out[((size_t)i * BT + b) * 3 + 0] = ox;
    out[((size_t)i * BT + b) * 3 + 1] = oy;
    out[((size_t)i * BT + b) * 3 + 2] = oz;
    ax = bx; ay = by; az = bz;
    bx = cx; by = cy; bz = cz;
    cx = ox; cy = oy; cz = oz;
  }
}

// ---------------- launch ----------------
extern "C" void kernel_launch(void* const* d_in, const int* in_sizes, int n_in,
                              void* d_out, int out_size, void* d_ws, size_t ws_size,
                              hipStream_t stream) {
  (void)in_sizes; (void)n_in; (void)out_size;
  const int*   primary = (const int*)d_in[0];
  const float* evo     = (const float*)d_in[1];
  const float* emb     = (const float*)d_in[3];
  const float* Wih0f   = (const float*)d_in[4];
  const float* Whh0f   = (const float*)d_in[5];
  const float* b0f     = (const float*)d_in[6];
  const float* Wih0b   = (const float*)d_in[7];
  const float* Whh0b   = (const float*)d_in[8];
  const float* b0b     = (const float*)d_in[9];
  const float* Wih1f   = (const float*)d_in[10];
  const float* Whh1f   = (const float*)d_in[11];
  const float* b1f     = (const float*)d_in[12];
  const float* Wih1b   = (const float*)d_in[13];
  const float* Whh1b   = (const float*)d_in[14];
  const float* b1b     = (const float*)d_in[15];
  const float* fcW     = (const float*)d_in[16];
  const float* fcb     = (const float*)d_in[17];
  const float* alpha   = (const float*)d_in[18];

  // ---- workspace sizing: mode 1 (6 xg slots, overlap) if it fits ----
  auto al = [](size_t n) { return (n + 511) & ~(size_t)511; };
  const size_t slotB = SLOT * 2;             // bytes per xg slot (20.5 MB)
  const size_t fixedB =
      al((size_t)TT * BT * 64 * 2) + al((size_t)BT * HROW * 2) +
      al((size_t)2 * 3200 * 64 * 2) + al((size_t)64 * 1664 * 2) +
      al(192 * 4) + al(192 * 4) + al((size_t)3 * TT * BT * 3 * 4) +
      al(11392 * 4) + 2 * al((size_t)TT * BT * HROW * 2);
  int slots = 6, mode = 1;
  if (fixedB + al((size_t)6 * slotB) > ws_size) { slots = 2; mode = 0; }

  char* ws = (char*)d_ws;
  size_t off = 0;
  auto take = [&](size_t n) -> void* {
    void* p = ws + off;
    off += (n + 511) & ~(size_t)511;
    return p;
  };
  __bf16* xpad = (__bf16*)take((size_t)TT * BT * 64 * 2);
  __bf16* zb   = (__bf16*)take((size_t)BT * HROW * 2);
  __bf16* wx0  = (__bf16*)take((size_t)2 * 3200 * 64 * 2);
  __bf16* wfc  = (__bf16*)take((size_t)64 * 1664 * 2);
  float*  sinA = (float*)take(192 * 4);
  float*  cosA = (float*)take(192 * 4);
  float*  pts  = (float*)take((size_t)3 * TT * BT * 3 * 4);
  u32*    flags0 = (u32*)take(11392 * 4);      // f0: 100 lines; f1: 256 lines
  u32*    flags1 = flags0 + 3200;
  __bf16* xg   = (__bf16*)take((size_t)slots * slotB);
  __bf16* h0   = (__bf16*)take((size_t)TT * BT * HROW * 2);
  __bf16* h1   = (__bf16*)take((size_t)TT * BT * HROW * 2);
  if (off > ws_size) return;  // failure signature: absmax == max|ref| == 233472

  static int lds_cfg = 0;
  if (!lds_cfg) {
    hipFuncSetAttribute((const void*)lstm_fused,
                        hipFuncAttributeMaxDynamicSharedMemorySize, LDS_FU);
    lds_cfg = 1;
  }

  pack_wx0_kernel<<<1600, 256, 0, stream>>>(Wih0f, Wih0b, wx0);
  pack_fc_kernel<<<(64 * 1664 + 255) / 256, 256, 0, stream>>>(fcW, wfc);
  xpad_kernel<<<(TT * BT * 64) / 256, 256, 0, stream>>>(primary, evo, emb, xpad);
  small_init_kernel<<<209, 256, 0, stream>>>(zb, flags0, sinA, cosA, alpha);

  FusedArgs fa;
  fa.xpad = xpad; fa.wx0 = wx0; fa.zero = zb;
  fa.Whh0f = Whh0f; fa.Whh0b = Whh0b; fa.b0f = b0f; fa.b0b = b0b;
  fa.Whh1f = Whh1f; fa.Whh1b = Whh1b;
  fa.Wih1f = Wih1f; fa.Wih1b = Wih1b;
  fa.b1f = b1f; fa.b1b = b1b;
  fa.h0 = h0; fa.h1 = h1; fa.xg = xg;
  fa.f0 = flags0; fa.f1 = flags1;
  fa.mode = mode;
  lstm_fused<<<256, 256, LDS_FU, stream>>>(fa);

  fc_kernel<<<TT, 256, 0, stream>>>(h1, xpad, wfc, fcb, sinA, cosA, pts);
  nerf_kernel<<<1, 64, 0, stream>>>(pts, (float*)d_out);
}

// Round 9
// 8441.498 us; speedup vs baseline: 1.0995x; 1.0735x over previous
//
#include <hip/hip_runtime.h>
#include <hip/hip_bf16.h>
#include <math.h>

// ---------------------------------------------------------------------------
// RGN model: T=700 B=32 H=800 EMB=32 EVO=21 A=60
// f32 in / f32 out; internal bf16 MFMA.
// R9: fused l0+l1 persistent kernel (256 WGs). R8 post-mortem: fused ==
// serial-sum exactly -> 6-slot mode (277 MB) almost surely fell back to
// 2-slot serial (ws < 277 MB; >=195 MB proven). This round sizes the overlap
// to 4 xg slots (236.2 MB total):
//   pre-produce chunks 6,7 (h0-complete at l0 gen 400) into slots s0,s1
//   during l0's tail; stream 0..5,8..13 through s2,s3 (s0,s1 reused after
//   chunks 6,7 consumed). P=[6,7,0,1,2,3,4,5,8..13]; WAIT[pos]=pos-4
//   occupant; deadlock-checked vs rec order 0..13.
// Decode: total ~8.4-8.7 -> mode 1 ran (ws>=236); ~9.05 -> mode 0 (ws<236).
// Rec/gemm inner bodies identical to R6/R8 (numerics unchanged).
// ---------------------------------------------------------------------------

typedef unsigned int u32;
typedef unsigned long long u64;
typedef __bf16 bf16x8 __attribute__((ext_vector_type(8)));
typedef float  f32x4  __attribute__((ext_vector_type(4)));

#define TT 700
#define BT 32
#define HROW 1664          // 800 fwd | 32 pad | 800 bwd | 32 pad
#define CH 50              // chunk length (14 chunks)
#define NCH (TT / CH)
#define SLOT ((size_t)2 * CH * 3200 * 32)      // bf16 elems per xg slot
#define LDS_FU (108 * 512 + 102400)   // 157,696 B (l0 layout, used by all)

__device__ __forceinline__ f32x4 mfma16(bf16x8 a, bf16x8 b, f32x4 c) {
  return __builtin_amdgcn_mfma_f32_16x16x32_bf16(a, b, c, 0, 0, 0);
}
__device__ __forceinline__ float sigf(float x) { return 1.f / (1.f + __expf(-x)); }

#define ALOAD(p)    __hip_atomic_load((p), __ATOMIC_RELAXED, __HIP_MEMORY_SCOPE_AGENT)
#define ASTORE(p,v) __hip_atomic_store((p), (v), __ATOMIC_RELAXED, __HIP_MEMORY_SCOPE_AGENT)

// LDS-only workgroup barrier: does NOT drain vmcnt.
__device__ __forceinline__ void lds_barrier() {
  asm volatile("s_waitcnt lgkmcnt(0)" ::: "memory");
  __builtin_amdgcn_s_barrier();
}

__device__ __forceinline__ bf16x8 cvt8(f32x4 a, f32x4 b) {
  bf16x8 r;
  r[0] = (__bf16)a[0]; r[1] = (__bf16)a[1]; r[2] = (__bf16)a[2]; r[3] = (__bf16)a[3];
  r[4] = (__bf16)b[0]; r[5] = (__bf16)b[1]; r[6] = (__bf16)b[2]; r[7] = (__bf16)b[3];
  return r;
}

// 4x4 transpose across lane quads (see R6).
#define QUAD_TRANSPOSE(l_, a0, a1, a2, a3, o0, o1, o2, o3)                   \
  {                                                                          \
    float s0 = __shfl_xor(a0, 1), s1 = __shfl_xor(a1, 1);                    \
    float s2 = __shfl_xor(a2, 1), s3 = __shfl_xor(a3, 1);                    \
    const bool e1 = ((l_) & 1) == 0;                                         \
    float n0 = e1 ? a0 : s1, n1 = e1 ? s0 : a1;                              \
    float n2 = e1 ? a2 : s3, n3 = e1 ? s2 : a3;                              \
    float t0 = __shfl_xor(n0, 2), t1 = __shfl_xor(n1, 2);                    \
    float t2 = __shfl_xor(n2, 2), t3 = __shfl_xor(n3, 2);                    \
    const bool e2 = ((l_) & 2) == 0;                                         \
    o0 = e2 ? n0 : t2; o1 = e2 ? n1 : t3;                                    \
    o2 = e2 ? t0 : n2; o3 = e2 ? t1 : n3;                                    \
  }

// ---------------- pack / init kernels ----------------
__global__ void pack_wx0_kernel(const float* Wih0f, const float* Wih0b, __bf16* wx0) {
  int idx = blockIdx.x * 256 + threadIdx.x;      // 2*3200*64 exact
  if (idx >= 2 * 3200 * 64) return;
  int d = idx / (3200 * 64);
  int r = (idx / 64) % 3200;
  int k = idx % 64;
  const float* W = d ? Wih0b : Wih0f;
  wx0[idx] = (k < 53) ? (__bf16)W[(size_t)r * 53 + k] : (__bf16)0.f;
}

__global__ void pack_fc_kernel(const float* fcW, __bf16* wfc) {
  int idx = blockIdx.x * 256 + threadIdx.x;
  if (idx >= 64 * 1664) return;
  int a = idx / 1664, k = idx % 1664;
  __bf16 v = (__bf16)0.f;
  if (a < 60 && k < 1653) v = (__bf16)fcW[(size_t)a * 1653 + k];
  wfc[idx] = v;
}

__global__ void xpad_kernel(const int* primary, const float* evo,
                            const float* emb, __bf16* xpad) {
  int idx = blockIdx.x * 256 + threadIdx.x;   // 700*32*64 exact
  int t = idx >> 11;
  int b = (idx >> 6) & 31;
  int k = idx & 63;
  __bf16 v = (__bf16)0.f;
  if (k < 32)      v = (__bf16)emb[primary[t * 32 + b] * 32 + k];
  else if (k < 53) v = (__bf16)evo[((size_t)t * 32 + b) * 21 + (k - 32)];
  xpad[idx] = v;
}

__global__ void small_init_kernel(__bf16* zerobuf, u32* flags,
                                  float* sinA, float* cosA, const float* alpha) {
  int idx = blockIdx.x * 256 + threadIdx.x;
  if (idx < 32 * HROW) zerobuf[idx] = (__bf16)0.f;
  if (idx < 11392) flags[idx] = 0u;   // f0: 100 lines; f1: 256 lines (x32 u32)
  int j = idx - 32 * HROW;
  if (j >= 0 && j < 192) {
    if (j < 180) {
      float v = alpha[j];
      sinA[j] = sinf(v);
      cosA[j] = cosf(v);
    } else { sinA[j] = 0.f; cosA[j] = 0.f; }
  }
}

// ---------------- flag helpers ----------------
__device__ __forceinline__ void wait_lines(u32* flags, int base, int count,
                                           unsigned gen) {
  const int tid = threadIdx.x;
  if (tid < 64) {
    int spin = 0;
    for (;;) {
      bool ok = true;
      for (int j = tid; j < count; j += 64)
        ok = ok && (ALOAD(flags + (size_t)(base + j) * 32) >= gen);
      if (__popcll(__ballot(ok)) == 64) break;
      if (++spin > 24) __builtin_amdgcn_s_sleep(1);
    }
  }
  __syncthreads();
}

__device__ __forceinline__ void rec_barrier(u32* flags, unsigned gen,
                                            int base, int count) {
  asm volatile("s_waitcnt vmcnt(0)" ::: "memory");
  __syncthreads();
  if (threadIdx.x == 0) ASTORE(flags + (size_t)blockIdx.x * 32, gen);
  wait_lines(flags, base, count, gen);
}

// ---------------- fused L0+L1 persistent kernel ----------------
struct FusedArgs {
  const __bf16 *xpad, *wx0, *zero;
  const float *Whh0f, *Whh0b, *b0f, *b0b;
  const float *Whh1f, *Whh1b, *Wih1f, *Wih1b, *b1f, *b1b;
  __bf16 *h0, *h1, *xg;
  u32 *f0, *f1;   // f0: l0 rec lines 0..99; f1: lines 0..99 rec, 100..255 gemm
  int mode;       // 1 = 4-slot (2 pre + 2 flow) overlap; 0 = 2-slot serial
};

__global__ __launch_bounds__(256, 1) void lstm_fused(FusedArgs A) {
  extern __shared__ __bf16 u2[];
  const int tid = threadIdx.x, w = tid >> 6, l = tid & 63;
  const int nidx = l & 15, q = l >> 4, bL = l & 31, gl = l >> 5;
  __bf16* wlds = u2 + 108 * 256;

  if (blockIdx.x < 100) {
    const int wg = blockIdx.x, d = wg / 50, u0 = (wg % 50) * 16;
    const int dcol = d * 832;
    // gate-interleaved row: N-slot nidx -> gate nidx&3, unit u0+4w+(nidx>>2)
    const int row = (nidx & 3) * 800 + u0 + 4 * w + (nidx >> 2);

    // ================= phase 1: L0 recurrence =================
    {
      const float bias_n = (d ? A.b0b : A.b0f)[row];
      const float* wrf = (d ? A.Whh0b : A.Whh0f) + (size_t)row * 800 + q * 8;
#pragma unroll
      for (int sl = 0; sl < 25; ++sl) {
        f32x4 wa = *(const f32x4*)(wrf + sl * 32);
        f32x4 wb = *(const f32x4*)(wrf + sl * 32 + 4);
        *(bf16x8*)(wlds + ((size_t)(w * 25 + sl) * 64 + l) * 8) = cvt8(wa, wb);
      }
      const __bf16* wx_row = A.wx0 + (size_t)d * 3200 * 64 + (size_t)row * 64 + q * 8;
      bf16x8 wx_r0 = *(const bf16x8*)wx_row;
      bf16x8 wx_r1 = *(const bf16x8*)(wx_row + 32);
      __syncthreads();

      float cA = 0.f, cB = 0.f;
#pragma unroll 1
      for (int s = 0; s < TT; ++s) {
        const int tt = d ? (TT - 1 - s) : s;
        const __bf16* hprev =
            (s == 0) ? A.zero : (A.h0 + (size_t)(d ? tt + 1 : tt - 1) * (BT * HROW));

        bf16x8 hreg[13];
        const __bf16* hsrc = hprev + (size_t)bL * HROW + dcol;
#pragma unroll
        for (int i = 0; i < 12; ++i)
          hreg[i] = *(const bf16x8*)(hsrc + (i * 8 + w * 2 + gl) * 8);
        if (w < 2) hreg[12] = *(const bf16x8*)(hsrc + (96 + w * 2 + gl) * 8);
        bf16x8 xv = *(const bf16x8*)(A.xpad + ((size_t)tt * BT + bL) * 64 + (tid >> 5) * 8);

#pragma unroll
        for (int i = 0; i < 12; ++i)
          *(bf16x8*)(u2 + (size_t)(i * 8 + w * 2 + gl) * 256 + bL * 8) = hreg[i];
        if (w < 2)
          *(bf16x8*)(u2 + (size_t)(96 + w * 2 + gl) * 256 + bL * 8) = hreg[12];
        *(bf16x8*)(u2 + (size_t)(100 + (tid >> 5)) * 256 + bL * 8) = xv;
        __syncthreads();

        f32x4 acc0 = {0.f, 0.f, 0.f, 0.f}, acc1 = {0.f, 0.f, 0.f, 0.f};
#pragma unroll
        for (int sl = 0; sl < 27; ++sl) {
          bf16x8 bfr;
          if (sl < 25)
            bfr = *(const bf16x8*)(wlds + ((size_t)(w * 25 + sl) * 64 + l) * 8);
          else
            bfr = (sl == 25) ? wx_r0 : wx_r1;
          const __bf16* ab = u2 + (size_t)(sl * 4 + q) * 256 + nidx * 8;
          bf16x8 a0 = *(const bf16x8*)ab;
          bf16x8 a1 = *(const bf16x8*)(ab + 128);
          acc0 = mfma16(a0, bfr, acc0);
          acc1 = mfma16(a1, bfr, acc1);
        }

        {
          float a0 = acc0[0] + bias_n, a1 = acc0[1] + bias_n,
                a2 = acc0[2] + bias_n, a3 = acc0[3] + bias_n;
          float e0 = acc1[0] + bias_n, e1v = acc1[1] + bias_n,
                e2v = acc1[2] + bias_n, e3 = acc1[3] + bias_n;
          float iA, fA, gA, oA, iB, fB, gB, oB;
          QUAD_TRANSPOSE(l, a0, a1, a2, a3, iA, fA, gA, oA);
          QUAD_TRANSPOSE(l, e0, e1v, e2v, e3, iB, fB, gB, oB);
          cA = sigf(fA) * cA + sigf(iA) * tanhf(gA);
          float hA = sigf(oA) * tanhf(cA);
          cB = sigf(fB) * cB + sigf(iB) * tanhf(gB);
          float hB = sigf(oB) * tanhf(cB);
          float hA2 = __shfl_xor(hA, 4);
          float hB2 = __shfl_xor(hB, 4);
          if ((l & 4) == 0) {
            const int bA = q * 4 + (nidx & 3);
            const int colp = dcol + u0 + 4 * w + (nidx >> 2);
            union { u32 u; __bf16 h2[2]; } pk;
            pk.h2[0] = (__bf16)hA; pk.h2[1] = (__bf16)hA2;
            ASTORE((u32*)(A.h0 + ((size_t)tt * BT + bA) * HROW + colp), pk.u);
            pk.h2[0] = (__bf16)hB; pk.h2[1] = (__bf16)hB2;
            ASTORE((u32*)(A.h0 + ((size_t)tt * BT + bA + 16) * HROW + colp), pk.u);
          }
        }

        if (s < TT - 1) rec_barrier(A.f0, (unsigned)(s + 1), d * 50, 50);
      }

      // final flag: h0 complete & visible (gen TT = 700)
      asm volatile("s_waitcnt vmcnt(0)" ::: "memory");
      __syncthreads();
      if (tid == 0) ASTORE(A.f0 + (size_t)wg * 32, (unsigned)TT);
    }

    // ================= phase 2: L1 recurrence =================
    {
      // rec consumption position of chunk k in production order P1
      const int POS1[14]  = {2, 3, 4, 5, 6, 7, 0, 1, 8, 9, 10, 11, 12, 13};
      const int SLOT1[14] = {2, 3, 2, 3, 2, 3, 0, 1, 2, 3, 0, 1, 2, 3};
      const float* wrf = (d ? A.Whh1b : A.Whh1f) + (size_t)row * 800 + q * 8;
      __syncthreads();
#pragma unroll
      for (int sl = 0; sl < 25; ++sl) {
        f32x4 wa = *(const f32x4*)(wrf + sl * 32);
        f32x4 wb = *(const f32x4*)(wrf + sl * 32 + 4);
        *(bf16x8*)(wlds + ((size_t)(w * 25 + sl) * 64 + l) * 8) = cvt8(wa, wb);
      }
      __syncthreads();
      float cA = 0.f, cB = 0.f;

      for (int k = 0; k < NCH; ++k) {
        // xg chunk k ready once all 156 gemm WGs produced its position
        const int pos = A.mode ? POS1[k] : k;
        wait_lines(A.f1, 100, 156, (unsigned)(pos + 1));
        const int slot = A.mode ? SLOT1[k] : (k & 1);
        const __bf16* buf = A.xg + (size_t)slot * SLOT;
        const u64* xga0 = (const u64*)(buf + ((size_t)(d * CH) * 3200 + row) * 32 + q * 4);
        u64 x0 = ALOAD(xga0);
        u64 x1 = ALOAD(xga0 + 4);
#pragma unroll 1
        for (int si = 0; si < CH; ++si) {
          const int s = k * CH + si;
          const int tt = d ? (TT - 1 - s) : s;
          const __bf16* hprev =
              (s == 0) ? A.zero
                       : (A.h1 + (size_t)(d ? tt + 1 : tt - 1) * (BT * HROW));

          u64 cx0 = x0, cx1 = x1;
          if (si + 1 < CH) {
            const u64* xgn = (const u64*)(buf +
                ((size_t)(d * CH + si + 1) * 3200 + row) * 32 + q * 4);
            x0 = ALOAD(xgn);
            x1 = ALOAD(xgn + 4);
          }

          bf16x8 hreg[13];
          const __bf16* hsrc = hprev + (size_t)bL * HROW + dcol;
#pragma unroll
          for (int i = 0; i < 12; ++i)
            hreg[i] = *(const bf16x8*)(hsrc + (i * 8 + w * 2 + gl) * 8);
          if (w < 2) hreg[12] = *(const bf16x8*)(hsrc + (96 + w * 2 + gl) * 8);

          union { u64 u; __bf16 h[4]; } ux0, ux1;
          ux0.u = cx0; ux1.u = cx1;
          f32x4 acc0 = {(float)ux0.h[0], (float)ux0.h[1],
                        (float)ux0.h[2], (float)ux0.h[3]};
          f32x4 acc1 = {(float)ux1.h[0], (float)ux1.h[1],
                        (float)ux1.h[2], (float)ux1.h[3]};

#pragma unroll
          for (int i = 0; i < 12; ++i)
            *(bf16x8*)(u2 + (size_t)(i * 8 + w * 2 + gl) * 256 + bL * 8) = hreg[i];
          if (w < 2)
            *(bf16x8*)(u2 + (size_t)(96 + w * 2 + gl) * 256 + bL * 8) = hreg[12];
          lds_barrier();   // LDS-only: keeps xg prefetch in flight

#pragma unroll
          for (int sl = 0; sl < 25; ++sl) {
            bf16x8 bfr = *(const bf16x8*)(wlds + ((size_t)(w * 25 + sl) * 64 + l) * 8);
            const __bf16* ab = u2 + (size_t)(sl * 4 + q) * 256 + nidx * 8;
            bf16x8 a0 = *(const bf16x8*)ab;
            bf16x8 a1 = *(const bf16x8*)(ab + 128);
            acc0 = mfma16(a0, bfr, acc0);
            acc1 = mfma16(a1, bfr, acc1);
          }

          {
            float a0 = acc0[0], a1 = acc0[1], a2 = acc0[2], a3 = acc0[3];
            float e0 = acc1[0], e1v = acc1[1], e2v = acc1[2], e3 = acc1[3];
            float iA, fA, gA, oA, iB, fB, gB, oB;
            QUAD_TRANSPOSE(l, a0, a1, a2, a3, iA, fA, gA, oA);
            QUAD_TRANSPOSE(l, e0, e1v, e2v, e3, iB, fB, gB, oB);
            cA = sigf(fA) * cA + sigf(iA) * tanhf(gA);
            float hA = sigf(oA) * tanhf(cA);
            cB = sigf(fB) * cB + sigf(iB) * tanhf(gB);
            float hB = sigf(oB) * tanhf(cB);
            float hA2 = __shfl_xor(hA, 4);
            float hB2 = __shfl_xor(hB, 4);
            if ((l & 4) == 0) {
              const int bA = q * 4 + (nidx & 3);
              const int colp = dcol + u0 + 4 * w + (nidx >> 2);
              union { u32 u; __bf16 h2[2]; } pk;
              pk.h2[0] = (__bf16)hA; pk.h2[1] = (__bf16)hA2;
              ASTORE((u32*)(A.h1 + ((size_t)tt * BT + bA) * HROW + colp), pk.u);
              pk.h2[0] = (__bf16)hB; pk.h2[1] = (__bf16)hB2;
              ASTORE((u32*)(A.h1 + ((size_t)tt * BT + bA + 16) * HROW + colp), pk.u);
            }
          }

          if (s < TT - 1) rec_barrier(A.f1, (unsigned)(s + 1), 0 + d * 50, 50);
        }
      }
    }
  } else {
    // ============ xg producer: 156 WGs, chases l0 ============
    // mode 1: P1 = [6,7, 0..5, 8..13]; chunks 6,7 pre-produced into s0,s1
    //   during l0's tail (gate gen 400); 0..5,8,9 flow through s2,s3;
    //   10..13 reuse s0..s3. WAIT1[pos] = chunk that previously occupied the
    //   slot (must be rec-consumed first); -1 = none. Deadlock-free: every
    //   wait-chunk < its chunk, rec consumes 0..13 in order.
    // mode 0: identity order, 2 slots, wait chunk ki-2 (serial).
    const int P1[14]    = {6, 7, 0, 1, 2, 3, 4, 5, 8, 9, 10, 11, 12, 13};
    const int WAIT1[14] = {-1,-1,-1,-1, 0, 1, 2, 3, 4, 5, 6, 7, 8, 9};
    const int SLOT1[14] = {2, 3, 2, 3, 2, 3, 0, 1, 2, 3, 0, 1, 2, 3};
    const int g = blockIdx.x - 100;
    const int u_begin = (g * 400) / 156;
    const int u_end   = ((g + 1) * 400) / 156;
    const int nslots  = (u_end - u_begin) * 50;
    const int rh = w >> 1, bh = w & 1;

    bf16x8 pre[13];
    f32x4 acc = {0.f, 0.f, 0.f, 0.f};
    int cur_tl = -1;
    float bn = 0.f;
    int rr = 0;

    for (int ki = 0; ki < NCH; ++ki) {
      const int k = A.mode ? P1[ki] : ki;
      // h0 chunk k complete at l0 gen max((k+1)*50, 700-k*50):
      // fwd half of row t written at s=t, bwd half at s=699-t.
      {
        const int n1 = (k + 1) * CH, n2 = TT - k * CH;
        wait_lines(A.f0, 0, 100, (unsigned)(n1 > n2 ? n1 : n2));
      }
      // slot reuse: wait until previous occupant chunk is consumed by rec
      const int wc = A.mode ? WAIT1[ki] : (ki - 2);
      if (wc >= 0) wait_lines(A.f1, 0, 100, (unsigned)((wc + 1) * CH));
      __bf16* buf = A.xg + (size_t)(A.mode ? SLOT1[k] : (k & 1)) * SLOT;

      // cold-load slot 0 of this chunk (u_begin, first tloc, pass 0)
      {
        const int th0 = u_begin & 1;
        const int dir0 = (u_begin >> 1) / 100;
        const int tloc0 = th0 * 25;
        const int t0 = dir0 ? (TT - 1 - k * CH - tloc0) : (k * CH + tloc0);
        const __bf16* hs = A.h0 + ((size_t)t0 * BT + bL) * HROW;
#pragma unroll
        for (int i = 0; i < 12; ++i)
          pre[i] = *(const bf16x8*)(hs + (i * 8 + w * 2 + gl) * 8);
        if (w < 2) pre[12] = *(const bf16x8*)(hs + (96 + w * 2 + gl) * 8);
      }

#pragma unroll 1
      for (int s = 0; s < nslots; ++s) {
        const int u = u_begin + s / 50;
        const int r = s % 50;
        const int tl = u >> 1, th = u & 1;
        const int tloc = th * 25 + (r >> 1);
        const int pass = r & 1;
        const int dir = tl / 100, rt = tl % 100;
        const int rbase = rt * 32;

        if (tl != cur_tl) {               // new W tile (only hit at pass==0)
          cur_tl = tl;
          const float* W = dir ? A.Wih1b : A.Wih1f;
          __syncthreads();   // protect wlds from previous tile's MFMAs
          for (int i = w * 25; i < w * 25 + 25; ++i) {
            const int rhh = i / 50, sl = i % 50;
            const int rrr = rbase + rhh * 16 + nidx;
            const float* wp = W + (size_t)rrr * 1600 + sl * 32 + q * 8;
            f32x4 wa = *(const f32x4*)wp;
            f32x4 wb = *(const f32x4*)(wp + 4);
            *(bf16x8*)(wlds + ((size_t)i * 64 + l) * 8) = cvt8(wa, wb);
          }
          __syncthreads();
          rr = rbase + rh * 16 + nidx;
          bn = (dir ? A.b1b : A.b1f)[rr];
        }

        // stage current slot's h0 rows (in pre) into u2
#pragma unroll
        for (int i = 0; i < 12; ++i)
          *(bf16x8*)(u2 + (size_t)(i * 8 + w * 2 + gl) * 256 + bL * 8) = pre[i];
        if (w < 2)
          *(bf16x8*)(u2 + (size_t)(96 + w * 2 + gl) * 256 + bL * 8) = pre[12];
        lds_barrier();   // A: staging visible; no vmcnt drain

        // issue NEXT slot's loads; latency hides under the MFMA chain below
        if (s + 1 < nslots) {
          const int s2 = s + 1;
          const int un = u_begin + s2 / 50;
          const int r2 = s2 % 50;
          const int thn = un & 1;
          const int tlocn = thn * 25 + (r2 >> 1);
          const int passn = r2 & 1;
          const int dirn = (un >> 1) / 100;
          const int tn = dirn ? (TT - 1 - k * CH - tlocn) : (k * CH + tlocn);
          const __bf16* hs = A.h0 + ((size_t)tn * BT + bL) * HROW + passn * 832;
#pragma unroll
          for (int i = 0; i < 12; ++i)
            pre[i] = *(const bf16x8*)(hs + (i * 8 + w * 2 + gl) * 8);
          if (w < 2) pre[12] = *(const bf16x8*)(hs + (96 + w * 2 + gl) * 8);
        }
        __builtin_amdgcn_sched_barrier(0);   // loads may not sink below here

        if (pass == 0) acc = f32x4{0.f, 0.f, 0.f, 0.f};
#pragma unroll
        for (int sl = 0; sl < 25; ++sl) {
          bf16x8 b = *(const bf16x8*)(wlds +
              ((size_t)(rh * 50 + pass * 25 + sl) * 64 + l) * 8);
          bf16x8 a = *(const bf16x8*)(u2 +
              (size_t)(sl * 4 + q) * 256 + (bh * 16 + nidx) * 8);
          acc = mfma16(a, b, acc);
        }
        lds_barrier();   // B: reads done; prefetch stays in flight

        if (pass == 1) {
          union { u64 u; __bf16 h[4]; } pv;
#pragma unroll
          for (int r2 = 0; r2 < 4; ++r2) pv.h[r2] = (__bf16)(acc[r2] + bn);
          ASTORE((u64*)(buf + ((size_t)(dir * CH + tloc) * 3200 + rr) * 32 +
                        bh * 16 + q * 4), pv.u);
        }
      }
      asm volatile("s_waitcnt vmcnt(0)" ::: "memory");   // xg at coherence pt
      __syncthreads();
      if (tid == 0) ASTORE(A.f1 + (size_t)(100 + g) * 32, (unsigned)(ki + 1));
    }
  }
}

// ---------------- FC + softmax + dihedral -> points ----------------
__global__ __launch_bounds__(256) void fc_kernel(
    const __bf16* __restrict__ h1, const __bf16* __restrict__ xpad,
    const __bf16* __restrict__ wfc, const float* __restrict__ fcb,
    const float* __restrict__ sinA, const float* __restrict__ cosA,
    float* __restrict__ pts) {
  __shared__ float lg[32 * 64];
  const int t = blockIdx.x, tid = threadIdx.x;
  const int wave = tid >> 6, lane = tid & 63, nidx = lane & 15, q = lane >> 4;
  const int a_col = wave * 16 + nidx;
  const __bf16* wrow = wfc + (size_t)a_col * 1664 + q * 8;
  const __bf16* h1row = h1 + (size_t)t * BT * HROW;
  const __bf16* xrow  = xpad + (size_t)t * BT * 64;
  f32x4 acc0 = {0.f, 0.f, 0.f, 0.f}, acc1 = {0.f, 0.f, 0.f, 0.f};
#pragma unroll
  for (int sl = 0; sl < 52; ++sl) {
    const int k = sl * 32 + q * 8;
    bf16x8 a0, a1;
    if (sl < 50) {
      const int kp = (sl < 25) ? k : (k + 32);
      a0 = *(const bf16x8*)(h1row + (size_t)nidx * HROW + kp);
      a1 = *(const bf16x8*)(h1row + (size_t)(16 + nidx) * HROW + kp);
    } else {
      a0 = *(const bf16x8*)(xrow + nidx * 64 + (k - 1600));
      a1 = *(const bf16x8*)(xrow + (16 + nidx) * 64 + (k - 1600));
    }
    bf16x8 bfr = *(const bf16x8*)(wrow + sl * 32);
    acc0 = mfma16(a0, bfr, acc0);
    acc1 = mfma16(a1, bfr, acc1);
  }
  const float bn = (a_col < 60) ? fcb[a_col] : -1e30f;
#pragma unroll
  for (int r = 0; r < 4; ++r) {
    lg[(q * 4 + r) * 64 + a_col]      = acc0[r] + bn;
    lg[(16 + q * 4 + r) * 64 + a_col] = acc1[r] + bn;
  }
  __syncthreads();

  const int b = tid >> 3, j = tid & 7;
  float v[8];
  float m = -1e30f;
#pragma unroll
  for (int k2 = 0; k2 < 8; ++k2) {
    v[k2] = lg[b * 64 + j + 8 * k2];
    m = fmaxf(m, v[k2]);
  }
  m = fmaxf(m, __shfl_xor(m, 1, 8));
  m = fmaxf(m, __shfl_xor(m, 2, 8));
  m = fmaxf(m, __shfl_xor(m, 4, 8));
  float s = 0.f;
#pragma unroll
  for (int k2 = 0; k2 < 8; ++k2) { v[k2] = __expf(v[k2] - m); s += v[k2]; }
  s += __shfl_xor(s, 1, 8);
  s += __shfl_xor(s, 2, 8);
  s += __shfl_xor(s, 4, 8);
  const float inv = 1.f / s;
  float ps[3] = {0.f, 0.f, 0.f}, pc[3] = {0.f, 0.f, 0.f};
#pragma unroll
  for (int k2 = 0; k2 < 8; ++k2) {
    const int a = j + 8 * k2;
    const float p = v[k2] * inv;
#pragma unroll
    for (int c = 0; c < 3; ++c) {
      ps[c] += p * sinA[a * 3 + c];
      pc[c] += p * cosA[a * 3 + c];
    }
  }
#pragma unroll
  for (int c = 0; c < 3; ++c) {
    ps[c] += __shfl_xor(ps[c], 1, 8);
    ps[c] += __shfl_xor(ps[c], 2, 8);
    ps[c] += __shfl_xor(ps[c], 4, 8);
    pc[c] += __shfl_xor(pc[c], 1, 8);
    pc[c] += __shfl_xor(pc[c], 2, 8);
    pc[c] += __shfl_xor(pc[c], 4, 8);
  }
  if (j == 0) {
    const float BL[3] = {145.801f, 152.326f, 132.868f};
    const float BA[3] = {2.124f, 1.941f, 2.028f};
#pragma unroll
    for (int c = 0; c < 3; ++c) {
      const float ang = 3.14159265358979323846f - BA[c];
      const float rct = BL[c] * cosf(ang), rst = BL[c] * sinf(ang);
      const float dih = atan2f(ps[c], pc[c]);
      float* o = pts + ((size_t)(3 * t + c) * BT + b) * 3;
      o[0] = rct;
      o[1] = cosf(dih) * rst;
      o[2] = sinf(dih) * rst;
    }
  }
}

// ---------------- sequential NeRF extension ----------------
__global__ void nerf_kernel(const float* __restrict__ pts, float* __restrict__ out) {
  const int b = threadIdx.x;
  if (b >= 32) return;
  float ax = -0.70710678f, ay = 1.22474487f, az = 0.f;
  float bx = -1.41421356f, by = 0.f, bz = 0.f;
  float cx = 0.f, cy = 0.f, cz = 0.f;
#pragma unroll 4
  for (int i = 0; i < 3 * TT; ++i) {
    const float* p = pts + ((size_t)i * BT + b) * 3;
    const float p0 = p[0], p1 = p[1], p2 = p[2];
    float ux = cx - bx, uy = cy - by, uz = cz - bz;
    const float ri = rsqrtf(ux * ux + uy * uy + uz * uz + 1e-12f);
    ux *= ri; uy *= ri; uz *= ri;
    const float wx = bx - ax, wy = by - ay, wz = bz - az;
    float nx = wy * uz - wz * uy, ny = wz * ux - wx * uz, nz = wx * uy - wy * ux;
    const float rn = rsqrtf(nx * nx + ny * ny + nz * nz + 1e-12f);
    nx *= rn; ny *= rn; nz *= rn;
    const float mx = ny * uz - nz * uy, my = nz * ux - nx * uz, mz = nx * uy - ny * ux;
    const float ox = cx + p0 * ux + p1 * mx + p2 * nx;
    const float oy = cy + p0 * uy + p1 * my + p2 * ny;
    const float oz = cz + p0 * uz + p1 * mz + p2 * nz;
    out[((size_t)i * BT + b) * 3 + 0] = ox;
    out[((size_t)i * BT + b) * 3 + 1] = oy;
    out[((size_t)i * BT + b) * 3 + 2] = oz;
    ax = bx; ay = by; az = bz;
    bx = cx; by = cy; bz = cz;
    cx = ox; cy = oy; cz = oz;
  }
}

// ---------------- launch ----------------
extern "C" void kernel_launch(void* const* d_in, const int* in_sizes, int n_in,
                              void* d_out, int out_size, void* d_ws, size_t ws_size,
                              hipStream_t stream) {
  (void)in_sizes; (void)n_in; (void)out_size;
  const int*   primary = (const int*)d_in[0];
  const float* evo     = (const float*)d_in[1];
  const float* emb     = (const float*)d_in[3];
  const float* Wih0f   = (const float*)d_in[4];
  const float* Whh0f   = (const float*)d_in[5];
  const float* b0f     = (const float*)d_in[6];
  const float* Wih0b   = (const float*)d_in[7];
  const float* Whh0b   = (const float*)d_in[8];
  const float* b0b     = (const float*)d_in[9];
  const float* Wih1f   = (const float*)d_in[10];
  const float* Whh1f   = (const float*)d_in[11];
  const float* b1f     = (const float*)d_in[12];
  const float* Wih1b   = (const float*)d_in[13];
  const float* Whh1b   = (const float*)d_in[14];
  const float* b1b     = (const float*)d_in[15];
  const float* fcW     = (const float*)d_in[16];
  const float* fcb     = (const float*)d_in[17];
  const float* alpha   = (const float*)d_in[18];

  // ---- workspace sizing: mode 1 (4 xg slots, 2-pre+2-flow) if it fits ----
  auto al = [](size_t n) { return (n + 511) & ~(size_t)511; };
  const size_t slotB = SLOT * 2;             // bytes per xg slot (20.5 MB)
  const size_t fixedB =
      al((size_t)TT * BT * 64 * 2) + al((size_t)BT * HROW * 2) +
      al((size_t)2 * 3200 * 64 * 2) + al((size_t)64 * 1664 * 2) +
      al(192 * 4) + al(192 * 4) + al((size_t)3 * TT * BT * 3 * 4) +
      al(11392 * 4) + 2 * al((size_t)TT * BT * HROW * 2);
  int slots = 4, mode = 1;
  if (fixedB + al((size_t)4 * slotB) > ws_size) { slots = 2; mode = 0; }

  char* ws = (char*)d_ws;
  size_t off = 0;
  auto take = [&](size_t n) -> void* {
    void* p = ws + off;
    off += (n + 511) & ~(size_t)511;
    return p;
  };
  __bf16* xpad = (__bf16*)take((size_t)TT * BT * 64 * 2);
  __bf16* zb   = (__bf16*)take((size_t)BT * HROW * 2);
  __bf16* wx0  = (__bf16*)take((size_t)2 * 3200 * 64 * 2);
  __bf16* wfc  = (__bf16*)take((size_t)64 * 1664 * 2);
  float*  sinA = (float*)take(192 * 4);
  float*  cosA = (float*)take(192 * 4);
  float*  pts  = (float*)take((size_t)3 * TT * BT * 3 * 4);
  u32*    flags0 = (u32*)take(11392 * 4);      // f0: 100 lines; f1: 256 lines
  u32*    flags1 = flags0 + 3200;
  __bf16* xg   = (__bf16*)take((size_t)slots * slotB);
  __bf16* h0   = (__bf16*)take((size_t)TT * BT * HROW * 2);
  __bf16* h1   = (__bf16*)take((size_t)TT * BT * HROW * 2);
  if (off > ws_size) return;  // failure signature: absmax == max|ref| == 233472

  static int lds_cfg = 0;
  if (!lds_cfg) {
    hipFuncSetAttribute((const void*)lstm_fused,
                        hipFuncAttributeMaxDynamicSharedMemorySize, LDS_FU);
    lds_cfg = 1;
  }

  pack_wx0_kernel<<<1600, 256, 0, stream>>>(Wih0f, Wih0b, wx0);
  pack_fc_kernel<<<(64 * 1664 + 255) / 256, 256, 0, stream>>>(fcW, wfc);
  xpad_kernel<<<(TT * BT * 64) / 256, 256, 0, stream>>>(primary, evo, emb, xpad);
  small_init_kernel<<<209, 256, 0, stream>>>(zb, flags0, sinA, cosA, alpha);

  FusedArgs fa;
  fa.xpad = xpad; fa.wx0 = wx0; fa.zero = zb;
  fa.Whh0f = Whh0f; fa.Whh0b = Whh0b; fa.b0f = b0f; fa.b0b = b0b;
  fa.Whh1f = Whh1f; fa.Whh1b = Whh1b;
  fa.Wih1f = Wih1f; fa.Wih1b = Wih1b;
  fa.b1f = b1f; fa.b1b = b1b;
  fa.h0 = h0; fa.h1 = h1; fa.xg = xg;
  fa.f0 = flags0; fa.f1 = flags1;
  fa.mode = mode;
  lstm_fused<<<256, 256, LDS_FU, stream>>>(fa);

  fc_kernel<<<TT, 256, 0, stream>>>(h1, xpad, wfc, fcb, sinA, cosA, pts);
  nerf_kernel<<<1, 64, 0, stream>>>(pts, (float*)d_out);
}